// Round 2
// 1892.215 us; speedup vs baseline: 1.1471x; 1.1471x over previous
//
#include <hip/hip_runtime.h>
#include <cstdio>
#include <cstdint>

#define B_   128
#define L_   512
#define H_   512
#define IN_  64
#define OUT_ 64
#define NH_  8
#define HD_  64
#define HOR_ 24

typedef unsigned short u16;
typedef __attribute__((ext_vector_type(8))) __bf16 bf16x8;
typedef __attribute__((ext_vector_type(4))) float f32x4;

__device__ __forceinline__ float bfbits2f(uint32_t hi){ union { uint32_t u; float f; } v; v.u = hi; return v.f; }
__device__ __forceinline__ float bf2f(u16 u){ union { uint32_t u; float f; } v; v.u = ((uint32_t)u) << 16; return v.f; }
__device__ __forceinline__ u16 f2bf(float f){
  union { uint32_t u; float f2; } v; v.f2 = f;
  uint32_t x = v.u;
  return (u16)((x + 0x7FFFu + ((x >> 16) & 1u)) >> 16);  // RNE
}

// ---------------- one-time prep ----------------

__global__ __launch_bounds__(256) void k_convert_x(const float4* __restrict__ X, ushort4* __restrict__ Xb, int n4){
  int i = blockIdx.x * blockDim.x + threadIdx.x;
  int stride = gridDim.x * blockDim.x;
  for (; i < n4; i += stride){
    float4 v = X[i];
    ushort4 o;
    o.x = f2bf(v.x); o.y = f2bf(v.y); o.z = f2bf(v.z); o.w = f2bf(v.w);
    Xb[i] = o;
  }
}

// fused small prep: block ranges
//  [0,129)      Mt (heavy: Wfc@Wo) + bcomb
//  [129,2177)   Wkv bf16 convert
//  [2177,6273)  Wt4b h-part (rows 512..1023 = W_hh, gate-interleaved)
//  [6273,7297)  Wqt transpose
//  [7297,7305)  bias4
//  [7305,7433)  xW0 = x0 @ W_ih^T (per-b blocks)
//  [7433,7945)  cbuf / hb0 init
__global__ __launch_bounds__(256) void k_prep(const float* __restrict__ Wk, const float* __restrict__ Wv,
                                              const float* __restrict__ W_ih, const float* __restrict__ W_hh,
                                              const float* __restrict__ b_ih, const float* __restrict__ b_hh,
                                              const float* __restrict__ Wq, const float* __restrict__ Wfc,
                                              const float* __restrict__ Wo, const float* __restrict__ bo,
                                              const float* __restrict__ bfc, const float* __restrict__ dec,
                                              const float* __restrict__ h0, const float* __restrict__ c0,
                                              u16* __restrict__ Wkv, float* __restrict__ Wt4b,
                                              float* __restrict__ Wqt, float* __restrict__ bias4,
                                              float* __restrict__ Mt, float* __restrict__ bcomb,
                                              float* __restrict__ xW0, float* __restrict__ hb0,
                                              float* __restrict__ cbuf){
  const int bid = blockIdx.x, tid = threadIdx.x;
  if (bid < 129){
    int i = bid * 256 + tid;
    if (i < 32768){
      int p = i >> 9, d = i & 511;
      float acc = 0.f;
      #pragma unroll 4
      for (int j = 0; j < 512; j++) acc += Wfc[p * 512 + j] * Wo[j * 512 + d];
      Mt[d * 64 + p] = acc;
    } else if (i < 32832){
      int p = i - 32768;
      float acc = bfc[p];
      for (int j = 0; j < 512; j++) acc += Wfc[p * 512 + j] * bo[j];
      bcomb[p] = acc;
    }
  } else if (bid < 2177){
    int i = (bid - 129) * 256 + tid;           // 1024*512
    int n = i >> 9;
    Wkv[i] = f2bf(n < 512 ? Wk[i] : Wv[i - 262144]);
  } else if (bid < 6273){
    int i = (bid - 2177) * 256 + tid;          // 512*512*4 -> W_hh into rows [512,1024)
    int kh = i >> 11, rem = i & 2047;
    int j = rem >> 2, g = rem & 3;
    Wt4b[((size_t)(512 + kh) * 512 + j) * 4 + g] = W_hh[(size_t)(g * 512 + j) * 512 + kh];
  } else if (bid < 7297){
    int i = (bid - 6273) * 256 + tid;          // 512*512
    int k = i >> 9, n = i & 511;
    Wqt[i] = Wq[n * 512 + k];
  } else if (bid < 7305){
    int i = (bid - 7297) * 256 + tid;          // 2048
    int j = i >> 2, g = i & 3;
    bias4[i] = b_ih[g * 512 + j] + b_hh[g * 512 + j];
  } else if (bid < 7433){
    // xW0[b][j*4+g] = sum_p dec[b][p] * W_ih[g*512+j][p]  (t=0 x-contribution)
    __shared__ float dv[64];
    int b = bid - 7305;
    if (tid < 64) dv[tid] = dec[b * 64 + tid];
    __syncthreads();
    #pragma unroll
    for (int q = 0; q < 8; q++){
      int o = tid * 8 + q;                     // 0..2047
      int j = o >> 2, g = o & 3;
      const float* wr = W_ih + (size_t)(g * 512 + j) * 64;
      float acc = 0.f;
      #pragma unroll
      for (int p = 0; p < 64; p += 4)
        acc += dv[p] * wr[p] + dv[p+1] * wr[p+1] + dv[p+2] * wr[p+2] + dv[p+3] * wr[p+3];
      xW0[(size_t)b * 2048 + o] = acc;
    }
  } else {
    int i = (bid - 7433) * 256 + tid;          // 65536 + 65536
    if (i < 65536) cbuf[i] = c0[i];
    else hb0[i - 65536] = h0[i - 65536];
  }
}

// prep2 (needs Mt, bcomb from k_prep):
//  [0,4096)  Wx = Mt @ W_ih^T -> Wt4b rows [0,512)
//  [4096]    biasx = bcomb @ W_ih^T
__global__ __launch_bounds__(256) void k_prep2(const float* __restrict__ Mt, const float* __restrict__ W_ih,
                                               const float* __restrict__ bcomb, float* __restrict__ Wt4b,
                                               float* __restrict__ biasx){
  const int bid = blockIdx.x, tid = threadIdx.x;
  if (bid < 4096){
    int i = bid * 256 + tid;                   // 512*2048
    int k = i >> 11, gcol = i & 2047;
    const float4* mr = (const float4*)(Mt + (size_t)k * 64);
    const float4* wr = (const float4*)(W_ih + (size_t)gcol * 64);
    float acc = 0.f;
    #pragma unroll
    for (int p = 0; p < 16; p++){
      float4 m = mr[p], w = wr[p];
      acc += m.x * w.x + m.y * w.y + m.z * w.z + m.w * w.w;
    }
    int g = gcol >> 9, j = gcol & 511;
    Wt4b[((size_t)k * 512 + j) * 4 + g] = acc;
  } else {
    #pragma unroll
    for (int q = 0; q < 8; q++){
      int o = tid * 8 + q;
      int j = o >> 2, g = o & 3;
      const float4* br = (const float4*)bcomb;
      const float4* wr = (const float4*)(W_ih + (size_t)(g * 512 + j) * 64);
      float acc = 0.f;
      #pragma unroll
      for (int p = 0; p < 16; p++){
        float4 b4 = br[p], w = wr[p];
        acc += b4.x * w.x + b4.y * w.y + b4.z * w.z + b4.w * w.w;
      }
      biasx[o] = acc;
    }
  }
}

// ---------------- phase 1: K/V projection (bf16 MFMA GEMM) ----------------
// XCD-aware mapping: flat = bx + 8*by -> xcd = bx. Each XCD gets a contiguous
// band of 64 m-tiles with all 8 n-tiles, so the shared A-tile stays in its L2.
__global__ __launch_bounds__(256) void k_gemm_kv(const u16* __restrict__ Xb, const u16* __restrict__ Wkv,
                                                 const float* __restrict__ bk, const float* __restrict__ bv,
                                                 u16* __restrict__ Kb, u16* __restrict__ Vb){
  __shared__ __align__(16) u16 As[128 * 64];
  __shared__ __align__(16) u16 Bs[128 * 64];
  const int tid = threadIdx.x;
  const int lane = tid & 63, wid = tid >> 6;
  const int wm = wid >> 1, wn = wid & 1;
  const int mt = blockIdx.x * 64 + (blockIdx.y >> 3);
  const int nt = blockIdx.y & 7;
  const int n0 = nt * 128, m0 = mt * 128;

  f32x4 zero = {0.f, 0.f, 0.f, 0.f};
  f32x4 acc[4][4];
  #pragma unroll
  for (int i = 0; i < 4; i++)
    #pragma unroll
    for (int j = 0; j < 4; j++) acc[i][j] = zero;

  for (int kt = 0; kt < 512; kt += 64){
    #pragma unroll
    for (int s = 0; s < 4; s++){
      int slot = tid + 256 * s;                // 0..1023
      int r = slot >> 3, cg = slot & 7;
      int sw = (cg ^ (r & 7)) << 3;
      *(uint4*)&As[r * 64 + sw] = *(const uint4*)&Xb[(size_t)(m0 + r) * 512 + kt + cg * 8];
      *(uint4*)&Bs[r * 64 + sw] = *(const uint4*)&Wkv[(size_t)(n0 + r) * 512 + kt + cg * 8];
    }
    __syncthreads();
    #pragma unroll
    for (int ks = 0; ks < 2; ks++){
      bf16x8 af[4], bfr[4];
      int g = ks * 4 + (lane >> 4);
      int ra = wm * 64 + (lane & 15);
      int rb = wn * 64 + (lane & 15);
      #pragma unroll
      for (int i = 0; i < 4; i++){
        int r = ra + i * 16;
        af[i] = *(const bf16x8*)&As[r * 64 + ((g ^ (r & 7)) << 3)];
      }
      #pragma unroll
      for (int j = 0; j < 4; j++){
        int r = rb + j * 16;
        bfr[j] = *(const bf16x8*)&Bs[r * 64 + ((g ^ (r & 7)) << 3)];
      }
      #pragma unroll
      for (int i = 0; i < 4; i++)
        #pragma unroll
        for (int j = 0; j < 4; j++)
          acc[i][j] = __builtin_amdgcn_mfma_f32_16x16x32_bf16(af[i], bfr[j], acc[i][j], 0, 0, 0);
    }
    __syncthreads();
  }

  #pragma unroll
  for (int j = 0; j < 4; j++){
    int n = n0 + wn * 64 + j * 16 + (lane & 15);
    float bias = (n < 512) ? bk[n] : bv[n - 512];
    u16* dst = (n < 512) ? Kb : Vb;
    int nh = (n >> 6) & 7, hd = n & 63;
    #pragma unroll
    for (int i = 0; i < 4; i++){
      #pragma unroll
      for (int r = 0; r < 4; r++){
        int m = m0 + wm * 64 + i * 16 + (lane >> 4) * 4 + r;
        int b = m >> 9, l = m & 511;
        float val = acc[i][j][r] + bias;
        dst[((size_t)((b * 8 + nh) * 512 + l)) * 64 + hd] = f2bf(val);
      }
    }
  }
}

// ---------------- per-step kernels ----------------

// gates GEMM 128 x 2048 x K=1024 over z = [ctx_{t-1}, h_{t-1}] + LSTM.
// 512 threads = 32 j x 16 ksplit; each thread register-blocks all 8 b-rows
// (acc[8] float4) so weight loads are shared 8x. shuffle(32) + LDS reduce
// (zs reused as psum). t=0: ctx=0, per-b bias = xW0 (x0 @ W_ih^T).
__global__ __launch_bounds__(512) void k_gates2(const float* __restrict__ ctxprev, const float* __restrict__ hprev,
                                                float* __restrict__ hnext, float* __restrict__ cbuf,
                                                const float4* __restrict__ Wt4b, const float4* __restrict__ bias4,
                                                const float4* __restrict__ biasx, const float4* __restrict__ xW0,
                                                int t0){
  __shared__ __align__(16) float zs[8 * 1024];       // 32 KB; reused as psum
  const int tid = threadIdx.x;
  const int jl = tid & 31, ks = tid >> 5;            // 32 j-lanes x 16 k-splits
  // XCD swizzle: same-jt blocks (sharing the W slice) colocate per XCD.
  const int bid = blockIdx.x;                        // 256 blocks
  const int xcd = bid & 7, idx = bid >> 3;
  const int jt = xcd * 2 + (idx & 1);
  const int bt = idx >> 1;
  const int b0 = bt * 8;
  const int j = jt * 32 + jl;

  // stage z = [ctx(512), h(512)] for 8 b-rows
  for (int i = tid; i < 8 * 256; i += 512){
    int r = i >> 8, c = (i & 255) << 2;
    float4 v;
    if (c < 512){
      if (!t0) v = *(const float4*)&ctxprev[(size_t)(b0 + r) * 512 + c];
      else     v = make_float4(0.f, 0.f, 0.f, 0.f);
    } else {
      v = *(const float4*)&hprev[(size_t)(b0 + r) * 512 + (c - 512)];
    }
    *(float4*)&zs[r * 1024 + c] = v;
  }
  __syncthreads();

  float4 acc[8];
  #pragma unroll
  for (int r = 0; r < 8; r++) acc[r] = make_float4(0.f, 0.f, 0.f, 0.f);

  const int k0 = ks * 64;
  const float4* Wp = Wt4b + (size_t)k0 * 512 + j;
  #pragma unroll 2
  for (int kk = 0; kk < 64; kk += 4){
    float4 w0 = Wp[(size_t)(kk + 0) * 512];
    float4 w1 = Wp[(size_t)(kk + 1) * 512];
    float4 w2 = Wp[(size_t)(kk + 2) * 512];
    float4 w3 = Wp[(size_t)(kk + 3) * 512];
    #pragma unroll
    for (int r = 0; r < 8; r++){
      const float4 xv = *(const float4*)&zs[r * 1024 + k0 + kk];
      acc[r].x += xv.x * w0.x; acc[r].y += xv.x * w0.y; acc[r].z += xv.x * w0.z; acc[r].w += xv.x * w0.w;
      acc[r].x += xv.y * w1.x; acc[r].y += xv.y * w1.y; acc[r].z += xv.y * w1.z; acc[r].w += xv.y * w1.w;
      acc[r].x += xv.z * w2.x; acc[r].y += xv.z * w2.y; acc[r].z += xv.z * w2.z; acc[r].w += xv.z * w2.w;
      acc[r].x += xv.w * w3.x; acc[r].y += xv.w * w3.y; acc[r].z += xv.w * w3.z; acc[r].w += xv.w * w3.w;
    }
  }

  // combine ks pairs within the wave, then 8 wave-partials via LDS
  #pragma unroll
  for (int r = 0; r < 8; r++){
    acc[r].x += __shfl_xor(acc[r].x, 32);
    acc[r].y += __shfl_xor(acc[r].y, 32);
    acc[r].z += __shfl_xor(acc[r].z, 32);
    acc[r].w += __shfl_xor(acc[r].w, 32);
  }
  __syncthreads();                                   // zs reads done; reuse as psum
  float4* ps = (float4*)zs;
  const int lane = tid & 63, wid = tid >> 6;
  if (lane < 32){
    #pragma unroll
    for (int r = 0; r < 8; r++) ps[(wid * 8 + r) * 32 + lane] = acc[r];
  }
  __syncthreads();

  if (tid < 256){
    const int r = tid >> 5, jj = tid & 31;
    const int j2 = jt * 32 + jj;
    float4 a = ps[r * 32 + jj];
    #pragma unroll
    for (int w = 1; w < 8; w++){
      float4 p = ps[(w * 8 + r) * 32 + jj];
      a.x += p.x; a.y += p.y; a.z += p.z; a.w += p.w;
    }
    const int b = b0 + r;
    float4 bb = bias4[j2];
    float4 bx = t0 ? xW0[(size_t)b * 512 + j2] : biasx[j2];
    float ai = a.x + bb.x + bx.x;
    float af = a.y + bb.y + bx.y;
    float ag = a.z + bb.z + bx.z;
    float ao = a.w + bb.w + bx.w;
    float c_old = cbuf[b * 512 + j2];
    float ig = 1.f / (1.f + __expf(-ai));
    float fg = 1.f / (1.f + __expf(-af));
    float e2 = __expf(2.f * ag);
    float gg = 1.f - 2.f / (e2 + 1.f);
    float og = 1.f / (1.f + __expf(-ao));
    float cn = fg * c_old + ig * gg;
    float ec = __expf(2.f * cn);
    float th = 1.f - 2.f / (ec + 1.f);
    cbuf[b * 512 + j2] = cn;
    hnext[b * 512 + j2] = og * th;
  }
}

// fused q-projection + attention. one block per (b,nh). writes ctx into
// the per-step slot of ctx_all (consumed by next gates + final pred GEMM).
__global__ __launch_bounds__(256) void k_attn(const float* __restrict__ hsrc, const float* __restrict__ Wqt,
                                              const float* __restrict__ bq, const u16* __restrict__ Kb,
                                              const u16* __restrict__ Vb, float* __restrict__ attn_out,
                                              float* __restrict__ ctx_t, int t){
  const int bx = blockIdx.x;
  const int b = bx >> 3, nh = bx & 7;
  const int tid = threadIdx.x;
  const int lane = tid & 63, wid = tid >> 6;
  __shared__ float hs[512];
  __shared__ float qred[4][64];
  __shared__ float qs[64];
  __shared__ float sc[512];
  __shared__ float red[16];
  __shared__ float ctxp[4][64];

  hs[tid] = hsrc[b * 512 + tid];
  hs[tid + 256] = hsrc[b * 512 + tid + 256];
  __syncthreads();

  // q[d] = bq + h . Wq[nh*64+d], k-split 4 ways; fold 1/sqrt(HD) into q.
  {
    const int d = tid & 63, part = tid >> 6;
    float qa = 0.f;
    const float* wp = Wqt + (size_t)(part * 128) * 512 + nh * 64 + d;
    const float* hp = &hs[part * 128];
    #pragma unroll 8
    for (int k = 0; k < 128; k++)
      qa += hp[k] * wp[(size_t)k * 512];
    qred[part][d] = qa;
  }
  __syncthreads();
  if (tid < 64)
    qs[tid] = (qred[0][tid] + qred[1][tid] + qred[2][tid] + qred[3][tid] + bq[nh * 64 + tid]) * 0.125f;
  __syncthreads();

  const u16* Kp = Kb + (size_t)bx * (512 * 64);
  float s[2];
  #pragma unroll
  for (int ii = 0; ii < 2; ii++){
    int l = tid + ii * 256;
    const u16* kr = Kp + l * 64;
    float acc = 0.f;
    #pragma unroll
    for (int g = 0; g < 8; g++){
      uint4 v = *(const uint4*)(kr + g * 8);
      const float* q8 = qs + g * 8;
      acc += bfbits2f(v.x << 16)          * q8[0];
      acc += bfbits2f(v.x & 0xffff0000u)  * q8[1];
      acc += bfbits2f(v.y << 16)          * q8[2];
      acc += bfbits2f(v.y & 0xffff0000u)  * q8[3];
      acc += bfbits2f(v.z << 16)          * q8[4];
      acc += bfbits2f(v.z & 0xffff0000u)  * q8[5];
      acc += bfbits2f(v.w << 16)          * q8[6];
      acc += bfbits2f(v.w & 0xffff0000u)  * q8[7];
    }
    s[ii] = acc;
  }
  float m = fmaxf(s[0], s[1]);
  for (int off = 32; off > 0; off >>= 1) m = fmaxf(m, __shfl_down(m, off));
  if (lane == 0) red[wid] = m;
  __syncthreads();
  if (tid == 0) red[8] = fmaxf(fmaxf(red[0], red[1]), fmaxf(red[2], red[3]));
  __syncthreads();
  float mx = red[8];
  float e0 = __expf(s[0] - mx), e1 = __expf(s[1] - mx);
  float ps = e0 + e1;
  for (int off = 32; off > 0; off >>= 1) ps += __shfl_down(ps, off);
  if (lane == 0) red[4 + wid] = ps;
  __syncthreads();
  if (tid == 0) red[9] = 1.f / (red[4] + red[5] + red[6] + red[7]);
  __syncthreads();
  float inv = red[9];
  float a0 = e0 * inv, a1 = e1 * inv;
  sc[tid] = a0; sc[tid + 256] = a1;
  float* aout = attn_out + ((size_t)bx * HOR_ + t) * 512;
  aout[tid] = a0; aout[tid + 256] = a1;
  __syncthreads();

  // ctx: part=wave covers 128 l; lane = (lh, dg): d pair, 2 rows/inst, uint loads.
  const u16* Vp = Vb + (size_t)bx * (512 * 64);
  const int part = wid;
  const int dg = lane & 31, lh = lane >> 5;
  const int d = dg * 2;
  float c0a = 0.f, c1a = 0.f;
  const u16* vp = Vp + (size_t)(part * 128 + lh) * 64 + d;
  #pragma unroll 8
  for (int i = 0; i < 64; i++){
    int l = part * 128 + i * 2 + lh;
    uint32_t v = *(const uint32_t*)(vp + (size_t)i * 128);
    float w = sc[l];
    c0a += w * bfbits2f(v << 16);
    c1a += w * bfbits2f(v & 0xffff0000u);
  }
  c0a += __shfl_xor(c0a, 32);
  c1a += __shfl_xor(c1a, 32);
  if (lh == 0){ ctxp[part][d] = c0a; ctxp[part][d + 1] = c1a; }
  __syncthreads();
  if (tid < 64)
    ctx_t[(size_t)b * 512 + nh * 64 + tid] = ctxp[0][tid] + ctxp[1][tid] + ctxp[2][tid] + ctxp[3][tid];
}

// batched pred (off critical path): pred[b][t] = ctx_all[t][b] @ Mt + bcomb
__global__ __launch_bounds__(256) void k_pred(const float* __restrict__ ctx_all, const float* __restrict__ Mt,
                                              const float* __restrict__ bcomb, float* __restrict__ outp){
  __shared__ float cs[512];
  __shared__ float pr[4][64];
  const int tid = threadIdx.x;
  const int b = blockIdx.x, t = blockIdx.y;
  const float* cx = ctx_all + ((size_t)t * B_ + b) * 512;
  cs[tid] = cx[tid];
  cs[tid + 256] = cx[tid + 256];
  __syncthreads();
  const int p = tid & 63, part = tid >> 6;
  float acc = 0.f;
  const float* mp = Mt + (size_t)(part * 128) * 64 + p;
  const float* cp = &cs[part * 128];
  #pragma unroll 8
  for (int i = 0; i < 128; i++)
    acc += cp[i] * mp[(size_t)i * 64];
  pr[part][p] = acc;
  __syncthreads();
  if (tid < 64){
    float v = pr[0][tid] + pr[1][tid] + pr[2][tid] + pr[3][tid] + bcomb[tid];
    outp[(size_t)b * (HOR_ * OUT_) + t * OUT_ + tid] = v;
  }
}

// ---------------- host launcher ----------------

extern "C" void kernel_launch(void* const* d_in, const int* in_sizes, int n_in,
                              void* d_out, int out_size, void* d_ws, size_t ws_size,
                              hipStream_t stream){
  const float* enc  = (const float*)d_in[0];
  const float* h0   = (const float*)d_in[1];
  const float* c0   = (const float*)d_in[2];
  const float* dec  = (const float*)d_in[3];
  const float* W_ih = (const float*)d_in[4];
  const float* W_hh = (const float*)d_in[5];
  const float* b_ih = (const float*)d_in[6];
  const float* b_hh = (const float*)d_in[7];
  const float* Wq   = (const float*)d_in[8];
  const float* bq   = (const float*)d_in[9];
  const float* Wk   = (const float*)d_in[10];
  const float* bk   = (const float*)d_in[11];
  const float* Wv   = (const float*)d_in[12];
  const float* bv   = (const float*)d_in[13];
  const float* Wo   = (const float*)d_in[14];
  const float* bo   = (const float*)d_in[15];
  const float* Wfc  = (const float*)d_in[16];
  const float* bfc  = (const float*)d_in[17];
  float* out = (float*)d_out;

  char* ws = (char*)d_ws;
  size_t off = 0;
  auto alloc = [&](size_t bytes){ void* p = ws + off; off += (bytes + 255) & ~(size_t)255; return p; };
  u16*   Xb    = (u16*)  alloc((size_t)B_ * L_ * H_ * 2);
  u16*   Kb    = (u16*)  alloc((size_t)B_ * NH_ * L_ * HD_ * 2);
  u16*   Vb    = (u16*)  alloc((size_t)B_ * NH_ * L_ * HD_ * 2);
  u16*   Wkv   = (u16*)  alloc((size_t)1024 * 512 * 2);
  float* Wt4b  = (float*)alloc((size_t)1024 * 512 * 4 * 4);   // [k][j][4 gates]
  float* Wqt   = (float*)alloc((size_t)512 * 512 * 4);
  float* Mt    = (float*)alloc((size_t)512 * 64 * 4);
  float* bcomb = (float*)alloc(64 * 4);
  float* bias4 = (float*)alloc((size_t)2048 * 4);
  float* biasx = (float*)alloc((size_t)2048 * 4);
  float* xW0   = (float*)alloc((size_t)B_ * 2048 * 4);
  float* hb0   = (float*)alloc((size_t)B_ * H_ * 4);
  float* hb1   = (float*)alloc((size_t)B_ * H_ * 4);
  float* cbuf  = (float*)alloc((size_t)B_ * H_ * 4);
  // ctx history aliases Xb: Xb is dead after k_gemm_kv; ctx_all is first
  // written by k_attn at t=0 (after k_gemm_kv in stream order).
  float* ctx_all = (float*)Xb;                // 24*128*512*4 = 6.3 MB << 67 MB
  if (off > ws_size){
    fprintf(stderr, "WORKSPACE TOO SMALL: need %zu, have %zu\n", off, ws_size);
  }

  float* out_pred = out;                                 // (B, HOR, OUT)
  float* out_attn = out + (size_t)B_ * HOR_ * OUT_;      // (B, NH, HOR, L)

  k_convert_x<<<4096, 256, 0, stream>>>((const float4*)enc, (ushort4*)Xb, (B_ * L_ * H_) / 4);
  k_prep<<<7945, 256, 0, stream>>>(Wk, Wv, W_ih, W_hh, b_ih, b_hh, Wq, Wfc, Wo, bo, bfc,
                                   dec, h0, c0, Wkv, Wt4b, Wqt, bias4, Mt, bcomb, xW0, hb0, cbuf);
  k_gemm_kv<<<dim3(8, 512), 256, 0, stream>>>(Xb, Wkv, bk, bv, Kb, Vb);
  k_prep2<<<4097, 256, 0, stream>>>(Mt, W_ih, bcomb, Wt4b, biasx);

  float* hb[2] = {hb0, hb1};
  for (int t = 0; t < HOR_; t++){
    const float* cprev = (t == 0) ? nullptr : (ctx_all + (size_t)(t - 1) * B_ * H_);
    k_gates2<<<256, 512, 0, stream>>>(cprev, hb[t & 1], hb[(t + 1) & 1], cbuf,
                                      (const float4*)Wt4b, (const float4*)bias4,
                                      (const float4*)biasx, (const float4*)xW0, t == 0 ? 1 : 0);
    k_attn<<<1024, 256, 0, stream>>>(hb[(t + 1) & 1], Wqt, bq, Kb, Vb, out_attn,
                                     ctx_all + (size_t)t * B_ * H_, t);
  }
  k_pred<<<dim3(128, 24), 256, 0, stream>>>(ctx_all, Mt, bcomb, out_pred);
}

// Round 3
// 1870.730 us; speedup vs baseline: 1.1603x; 1.0115x over previous
//
#include <hip/hip_runtime.h>
#include <hip/hip_cooperative_groups.h>
#include <cstdio>
#include <cstdint>

namespace cg = cooperative_groups;

#define B_   128
#define L_   512
#define H_   512
#define IN_  64
#define OUT_ 64
#define NH_  8
#define HD_  64
#define HOR_ 24

typedef unsigned short u16;
typedef __attribute__((ext_vector_type(8))) __bf16 bf16x8;
typedef __attribute__((ext_vector_type(4))) float f32x4;

__device__ __forceinline__ float bfbits2f(uint32_t hi){ union { uint32_t u; float f; } v; v.u = hi; return v.f; }
__device__ __forceinline__ u16 f2bf(float f){
  union { uint32_t u; float f2; } v; v.f2 = f;
  uint32_t x = v.u;
  return (u16)((x + 0x7FFFu + ((x >> 16) & 1u)) >> 16);  // RNE
}

// ---------------- one-time prep ----------------

__global__ __launch_bounds__(256) void k_convert_x(const float4* __restrict__ X, ushort4* __restrict__ Xb, int n4){
  int i = blockIdx.x * blockDim.x + threadIdx.x;
  int stride = gridDim.x * blockDim.x;
  for (; i < n4; i += stride){
    float4 v = X[i];
    ushort4 o;
    o.x = f2bf(v.x); o.y = f2bf(v.y); o.z = f2bf(v.z); o.w = f2bf(v.w);
    Xb[i] = o;
  }
}

// fused small prep: block ranges (see round-2 comments)
__global__ __launch_bounds__(256) void k_prep(const float* __restrict__ Wk, const float* __restrict__ Wv,
                                              const float* __restrict__ W_ih, const float* __restrict__ W_hh,
                                              const float* __restrict__ b_ih, const float* __restrict__ b_hh,
                                              const float* __restrict__ Wq, const float* __restrict__ Wfc,
                                              const float* __restrict__ Wo, const float* __restrict__ bo,
                                              const float* __restrict__ bfc, const float* __restrict__ dec,
                                              const float* __restrict__ h0, const float* __restrict__ c0,
                                              u16* __restrict__ Wkv, float* __restrict__ Wt4b,
                                              float* __restrict__ Wqt, float* __restrict__ bias4,
                                              float* __restrict__ Mt, float* __restrict__ bcomb,
                                              float* __restrict__ xW0, float* __restrict__ hb0,
                                              float* __restrict__ cbuf){
  const int bid = blockIdx.x, tid = threadIdx.x;
  if (bid < 129){
    int i = bid * 256 + tid;
    if (i < 32768){
      int p = i >> 9, d = i & 511;
      float acc = 0.f;
      #pragma unroll 4
      for (int j = 0; j < 512; j++) acc += Wfc[p * 512 + j] * Wo[j * 512 + d];
      Mt[d * 64 + p] = acc;
    } else if (i < 32832){
      int p = i - 32768;
      float acc = bfc[p];
      for (int j = 0; j < 512; j++) acc += Wfc[p * 512 + j] * bo[j];
      bcomb[p] = acc;
    }
  } else if (bid < 2177){
    int i = (bid - 129) * 256 + tid;           // 1024*512
    int n = i >> 9;
    Wkv[i] = f2bf(n < 512 ? Wk[i] : Wv[i - 262144]);
  } else if (bid < 6273){
    int i = (bid - 2177) * 256 + tid;          // 512*512*4 -> W_hh into rows [512,1024)
    int kh = i >> 11, rem = i & 2047;
    int j = rem >> 2, g = rem & 3;
    Wt4b[((size_t)(512 + kh) * 512 + j) * 4 + g] = W_hh[(size_t)(g * 512 + j) * 512 + kh];
  } else if (bid < 7297){
    int i = (bid - 6273) * 256 + tid;          // 512*512
    int k = i >> 9, n = i & 511;
    Wqt[i] = Wq[n * 512 + k];
  } else if (bid < 7305){
    int i = (bid - 7297) * 256 + tid;          // 2048
    int j = i >> 2, g = i & 3;
    bias4[i] = b_ih[g * 512 + j] + b_hh[g * 512 + j];
  } else if (bid < 7433){
    // xW0[b][j*4+g] = sum_p dec[b][p] * W_ih[g*512+j][p]  (t=0 x-contribution)
    __shared__ float dv[64];
    int b = bid - 7305;
    if (tid < 64) dv[tid] = dec[b * 64 + tid];
    __syncthreads();
    #pragma unroll
    for (int q = 0; q < 8; q++){
      int o = tid * 8 + q;                     // 0..2047
      int j = o >> 2, g = o & 3;
      const float* wr = W_ih + (size_t)(g * 512 + j) * 64;
      float acc = 0.f;
      #pragma unroll
      for (int p = 0; p < 64; p += 4)
        acc += dv[p] * wr[p] + dv[p+1] * wr[p+1] + dv[p+2] * wr[p+2] + dv[p+3] * wr[p+3];
      xW0[(size_t)b * 2048 + o] = acc;
    }
  } else {
    int i = (bid - 7433) * 256 + tid;          // 65536 + 65536
    if (i < 65536) cbuf[i] = c0[i];
    else hb0[i - 65536] = h0[i - 65536];
  }
}

// prep2 (needs Mt, bcomb from k_prep)
__global__ __launch_bounds__(256) void k_prep2(const float* __restrict__ Mt, const float* __restrict__ W_ih,
                                               const float* __restrict__ bcomb, float* __restrict__ Wt4b,
                                               float* __restrict__ biasx){
  const int bid = blockIdx.x, tid = threadIdx.x;
  if (bid < 4096){
    int i = bid * 256 + tid;                   // 512*2048
    int k = i >> 11, gcol = i & 2047;
    const float4* mr = (const float4*)(Mt + (size_t)k * 64);
    const float4* wr = (const float4*)(W_ih + (size_t)gcol * 64);
    float acc = 0.f;
    #pragma unroll
    for (int p = 0; p < 16; p++){
      float4 m = mr[p], w = wr[p];
      acc += m.x * w.x + m.y * w.y + m.z * w.z + m.w * w.w;
    }
    int g = gcol >> 9, j = gcol & 511;
    Wt4b[((size_t)k * 512 + j) * 4 + g] = acc;
  } else {
    #pragma unroll
    for (int q = 0; q < 8; q++){
      int o = tid * 8 + q;
      int j = o >> 2, g = o & 3;
      const float4* br = (const float4*)bcomb;
      const float4* wr = (const float4*)(W_ih + (size_t)(g * 512 + j) * 64);
      float acc = 0.f;
      #pragma unroll
      for (int p = 0; p < 16; p++){
        float4 b4 = br[p], w = wr[p];
        acc += b4.x * w.x + b4.y * w.y + b4.z * w.z + b4.w * w.w;
      }
      biasx[o] = acc;
    }
  }
}

// ---------------- K/V projection (bf16 MFMA GEMM, XCD-banded) ----------------
__global__ __launch_bounds__(256) void k_gemm_kv(const u16* __restrict__ Xb, const u16* __restrict__ Wkv,
                                                 const float* __restrict__ bk, const float* __restrict__ bv,
                                                 u16* __restrict__ Kb, u16* __restrict__ Vb){
  __shared__ __align__(16) u16 As[128 * 64];
  __shared__ __align__(16) u16 Bs[128 * 64];
  const int tid = threadIdx.x;
  const int lane = tid & 63, wid = tid >> 6;
  const int wm = wid >> 1, wn = wid & 1;
  const int mt = blockIdx.x * 64 + (blockIdx.y >> 3);
  const int nt = blockIdx.y & 7;
  const int n0 = nt * 128, m0 = mt * 128;

  f32x4 zero = {0.f, 0.f, 0.f, 0.f};
  f32x4 acc[4][4];
  #pragma unroll
  for (int i = 0; i < 4; i++)
    #pragma unroll
    for (int j = 0; j < 4; j++) acc[i][j] = zero;

  for (int kt = 0; kt < 512; kt += 64){
    #pragma unroll
    for (int s = 0; s < 4; s++){
      int slot = tid + 256 * s;                // 0..1023
      int r = slot >> 3, cg = slot & 7;
      int sw = (cg ^ (r & 7)) << 3;
      *(uint4*)&As[r * 64 + sw] = *(const uint4*)&Xb[(size_t)(m0 + r) * 512 + kt + cg * 8];
      *(uint4*)&Bs[r * 64 + sw] = *(const uint4*)&Wkv[(size_t)(n0 + r) * 512 + kt + cg * 8];
    }
    __syncthreads();
    #pragma unroll
    for (int ks = 0; ks < 2; ks++){
      bf16x8 af[4], bfr[4];
      int g = ks * 4 + (lane >> 4);
      int ra = wm * 64 + (lane & 15);
      int rb = wn * 64 + (lane & 15);
      #pragma unroll
      for (int i = 0; i < 4; i++){
        int r = ra + i * 16;
        af[i] = *(const bf16x8*)&As[r * 64 + ((g ^ (r & 7)) << 3)];
      }
      #pragma unroll
      for (int j = 0; j < 4; j++){
        int r = rb + j * 16;
        bfr[j] = *(const bf16x8*)&Bs[r * 64 + ((g ^ (r & 7)) << 3)];
      }
      #pragma unroll
      for (int i = 0; i < 4; i++)
        #pragma unroll
        for (int j = 0; j < 4; j++)
          acc[i][j] = __builtin_amdgcn_mfma_f32_16x16x32_bf16(af[i], bfr[j], acc[i][j], 0, 0, 0);
    }
    __syncthreads();
  }

  #pragma unroll
  for (int j = 0; j < 4; j++){
    int n = n0 + wn * 64 + j * 16 + (lane & 15);
    float bias = (n < 512) ? bk[n] : bv[n - 512];
    u16* dst = (n < 512) ? Kb : Vb;
    int nh = (n >> 6) & 7, hd = n & 63;
    #pragma unroll
    for (int i = 0; i < 4; i++){
      #pragma unroll
      for (int r = 0; r < 4; r++){
        int m = m0 + wm * 64 + i * 16 + (lane >> 4) * 4 + r;
        int b = m >> 9, l = m & 511;
        float val = acc[i][j][r] + bias;
        dst[((size_t)((b * 8 + nh) * 512 + l)) * 64 + hd] = f2bf(val);
      }
    }
  }
}

// ---------------- persistent cooperative loop kernel ----------------
// grid = 1024 blocks x 256 thr (4 blocks/CU co-resident). Block beta = (b,nh).
// Registers hold K rows (l=tid,tid+256; 64 VGPR) and V cols (64 VGPR) for all
// 24 steps -> K/V global traffic happens ONCE instead of 24x.
// Per step: gates phase (blocks 0..255: 16 bt x 16 jt; 8 b-rows reg-blocked,
// 8-way k-split, K=1024 over z=[ctx,h]) -> grid.sync -> attn (all blocks,
// scores/ctx from regs) -> grid.sync.
__global__ __launch_bounds__(256, 4) void k_loop(const float* __restrict__ Wqt, const float* __restrict__ bq,
                                                 const u16* __restrict__ Kb, const u16* __restrict__ Vb,
                                                 const float4* __restrict__ Wt4b, const float4* __restrict__ bias4,
                                                 const float4* __restrict__ biasx, const float4* __restrict__ xW0,
                                                 float* __restrict__ hb0, float* __restrict__ hb1,
                                                 float* __restrict__ cbuf, float* __restrict__ ctx_all,
                                                 float* __restrict__ attn_out){
  cg::grid_group grid = cg::this_grid();
  __shared__ __align__(16) float sm[8 * 1024];       // 32 KB pool (zs / psum / attn bufs)

  const int beta = blockIdx.x;
  const int tid = threadIdx.x;
  const int lane = tid & 63, wid = tid >> 6;
  const int b = beta >> 3, nh = beta & 7;

  // ---- K into registers: 2 rows (l = tid, tid+256), 64 bf16 each ----
  const u16* Kp = Kb + (size_t)beta * (512 * 64);
  uint4 kr0[8], kr1[8];
  #pragma unroll
  for (int g = 0; g < 8; g++){
    kr0[g] = *(const uint4*)(Kp + (size_t)tid * 64 + g * 8);
    kr1[g] = *(const uint4*)(Kp + (size_t)(tid + 256) * 64 + g * 8);
  }
  // ---- V into registers: (part,lh,dg): 64 l-samples of d-pair ----
  const int part = wid;
  const int dg = lane & 31, lh = lane >> 5;
  const int d = dg * 2;
  const u16* vp = Vb + (size_t)beta * (512 * 64) + (size_t)(part * 128 + lh) * 64 + d;
  uint32_t vr[64];
  #pragma unroll
  for (int i = 0; i < 64; i++) vr[i] = *(const uint32_t*)(vp + (size_t)i * 128);

  // gates identity (blocks 0..255 active)
  const bool g_active = (beta < 256);
  const int bt = beta >> 4, jt = beta & 15;
  const int b0 = bt * 8;
  const int jl = tid & 31, ks = tid >> 5;            // 32 j x 8 k-splits

  #pragma unroll 1
  for (int t = 0; t < HOR_; t++){
    const float* hprev = (t & 1) ? hb1 : hb0;
    float* hnext = (t & 1) ? hb0 : hb1;

    // ---------------- gates ----------------
    if (g_active){
      // stage z = [ctx(512), h(512)] for 8 b-rows into sm
      const float* cprev = ctx_all + (size_t)(t - 1) * (B_ * H_);
      for (int i = tid; i < 2048; i += 256){
        int r = i >> 8, c = (i & 255) << 2;
        float4 v;
        if (c < 512){
          if (t) v = *(const float4*)&cprev[(size_t)(b0 + r) * 512 + c];
          else   v = make_float4(0.f, 0.f, 0.f, 0.f);
        } else {
          v = *(const float4*)&hprev[(size_t)(b0 + r) * 512 + (c - 512)];
        }
        *(float4*)&sm[r * 1024 + c] = v;
      }
      __syncthreads();

      float4 acc[8];
      #pragma unroll
      for (int r = 0; r < 8; r++) acc[r] = make_float4(0.f, 0.f, 0.f, 0.f);
      const int k0 = ks * 128;
      const float4* Wp = Wt4b + (size_t)k0 * 512 + jt * 32 + jl;
      #pragma unroll 2
      for (int kk = 0; kk < 128; kk += 4){
        float4 w0 = Wp[(size_t)(kk + 0) * 512];
        float4 w1 = Wp[(size_t)(kk + 1) * 512];
        float4 w2 = Wp[(size_t)(kk + 2) * 512];
        float4 w3 = Wp[(size_t)(kk + 3) * 512];
        #pragma unroll
        for (int r = 0; r < 8; r++){
          const float4 xv = *(const float4*)&sm[r * 1024 + k0 + kk];
          acc[r].x += xv.x * w0.x; acc[r].y += xv.x * w0.y; acc[r].z += xv.x * w0.z; acc[r].w += xv.x * w0.w;
          acc[r].x += xv.y * w1.x; acc[r].y += xv.y * w1.y; acc[r].z += xv.y * w1.z; acc[r].w += xv.y * w1.w;
          acc[r].x += xv.z * w2.x; acc[r].y += xv.z * w2.y; acc[r].z += xv.z * w2.z; acc[r].w += xv.z * w2.w;
          acc[r].x += xv.w * w3.x; acc[r].y += xv.w * w3.y; acc[r].z += xv.w * w3.z; acc[r].w += xv.w * w3.w;
        }
      }
      // merge ks pairs within wave (lanes 0-31 <-> 32-63), 4 wave partials via LDS
      #pragma unroll
      for (int r = 0; r < 8; r++){
        acc[r].x += __shfl_xor(acc[r].x, 32);
        acc[r].y += __shfl_xor(acc[r].y, 32);
        acc[r].z += __shfl_xor(acc[r].z, 32);
        acc[r].w += __shfl_xor(acc[r].w, 32);
      }
      __syncthreads();                               // sm reads done; reuse as psum
      float4* ps = (float4*)sm;
      if (lane < 32){
        #pragma unroll
        for (int r = 0; r < 8; r++) ps[(wid * 8 + r) * 32 + jl] = acc[r];
      }
      __syncthreads();
      {
        const int r = tid >> 5, jj = tid & 31;
        const int j2 = jt * 32 + jj;
        float4 a = ps[r * 32 + jj];
        #pragma unroll
        for (int w = 1; w < 4; w++){
          float4 p = ps[(w * 8 + r) * 32 + jj];
          a.x += p.x; a.y += p.y; a.z += p.z; a.w += p.w;
        }
        const int bb_ = b0 + r;
        float4 bb = bias4[j2];
        float4 bx = (t == 0) ? xW0[(size_t)bb_ * 512 + j2] : biasx[j2];
        float ai = a.x + bb.x + bx.x;
        float af = a.y + bb.y + bx.y;
        float ag = a.z + bb.z + bx.z;
        float ao = a.w + bb.w + bx.w;
        float c_old = cbuf[bb_ * 512 + j2];
        float ig = 1.f / (1.f + __expf(-ai));
        float fg = 1.f / (1.f + __expf(-af));
        float e2 = __expf(2.f * ag);
        float gg = 1.f - 2.f / (e2 + 1.f);
        float og = 1.f / (1.f + __expf(-ao));
        float cn = fg * c_old + ig * gg;
        float ec = __expf(2.f * cn);
        float th = 1.f - 2.f / (ec + 1.f);
        cbuf[bb_ * 512 + j2] = cn;
        hnext[bb_ * 512 + j2] = og * th;
      }
    }
    grid.sync();

    // ---------------- attention (all blocks) ----------------
    float* hs   = sm;            // [512]
    float* qred = sm + 512;      // [4][64]
    float* qs   = sm + 768;      // [64]
    float* sc   = sm + 832;      // [512]
    float* red  = sm + 1344;     // [16]
    float* ctxp = sm + 1360;     // [4][64]

    hs[tid] = hnext[b * 512 + tid];
    hs[tid + 256] = hnext[b * 512 + tid + 256];
    __syncthreads();

    {
      const int dd = tid & 63, pp = tid >> 6;
      float qa = 0.f;
      const float* wp = Wqt + (size_t)(pp * 128) * 512 + nh * 64 + dd;
      const float* hp = &hs[pp * 128];
      #pragma unroll 8
      for (int k = 0; k < 128; k++)
        qa += hp[k] * wp[(size_t)k * 512];
      qred[pp * 64 + dd] = qa;
    }
    __syncthreads();
    if (tid < 64)
      qs[tid] = (qred[tid] + qred[64 + tid] + qred[128 + tid] + qred[192 + tid] + bq[nh * 64 + tid]) * 0.125f;
    __syncthreads();

    float s0 = 0.f, s1 = 0.f;
    #pragma unroll
    for (int g = 0; g < 8; g++){
      const float* q8 = qs + g * 8;
      uint4 v = kr0[g];
      s0 += bfbits2f(v.x << 16)          * q8[0];
      s0 += bfbits2f(v.x & 0xffff0000u)  * q8[1];
      s0 += bfbits2f(v.y << 16)          * q8[2];
      s0 += bfbits2f(v.y & 0xffff0000u)  * q8[3];
      s0 += bfbits2f(v.z << 16)          * q8[4];
      s0 += bfbits2f(v.z & 0xffff0000u)  * q8[5];
      s0 += bfbits2f(v.w << 16)          * q8[6];
      s0 += bfbits2f(v.w & 0xffff0000u)  * q8[7];
      uint4 w = kr1[g];
      s1 += bfbits2f(w.x << 16)          * q8[0];
      s1 += bfbits2f(w.x & 0xffff0000u)  * q8[1];
      s1 += bfbits2f(w.y << 16)          * q8[2];
      s1 += bfbits2f(w.y & 0xffff0000u)  * q8[3];
      s1 += bfbits2f(w.z << 16)          * q8[4];
      s1 += bfbits2f(w.z & 0xffff0000u)  * q8[5];
      s1 += bfbits2f(w.w << 16)          * q8[6];
      s1 += bfbits2f(w.w & 0xffff0000u)  * q8[7];
    }
    float m = fmaxf(s0, s1);
    for (int off = 32; off > 0; off >>= 1) m = fmaxf(m, __shfl_down(m, off));
    if (lane == 0) red[wid] = m;
    __syncthreads();
    if (tid == 0) red[8] = fmaxf(fmaxf(red[0], red[1]), fmaxf(red[2], red[3]));
    __syncthreads();
    float mx = red[8];
    float e0 = __expf(s0 - mx), e1 = __expf(s1 - mx);
    float psum = e0 + e1;
    for (int off = 32; off > 0; off >>= 1) psum += __shfl_down(psum, off);
    if (lane == 0) red[4 + wid] = psum;
    __syncthreads();
    if (tid == 0) red[9] = 1.f / (red[4] + red[5] + red[6] + red[7]);
    __syncthreads();
    float inv = red[9];
    float a0 = e0 * inv, a1 = e1 * inv;
    sc[tid] = a0; sc[tid + 256] = a1;
    float* aout = attn_out + ((size_t)beta * HOR_ + t) * 512;
    aout[tid] = a0; aout[tid + 256] = a1;
    __syncthreads();

    float c0a = 0.f, c1a = 0.f;
    #pragma unroll
    for (int i = 0; i < 64; i++){
      int l = part * 128 + i * 2 + lh;
      uint32_t v = vr[i];
      float w = sc[l];
      c0a += w * bfbits2f(v << 16);
      c1a += w * bfbits2f(v & 0xffff0000u);
    }
    c0a += __shfl_xor(c0a, 32);
    c1a += __shfl_xor(c1a, 32);
    if (lh == 0){ ctxp[part * 64 + d] = c0a; ctxp[part * 64 + d + 1] = c1a; }
    __syncthreads();
    if (tid < 64)
      ctx_all[(size_t)t * (B_ * H_) + b * 512 + nh * 64 + tid] =
        ctxp[tid] + ctxp[64 + tid] + ctxp[128 + tid] + ctxp[192 + tid];
    grid.sync();
  }
}

// ---------------- fallback per-step kernels (round-2 verified) ----------------

__global__ __launch_bounds__(512) void k_gates2(const float* __restrict__ ctxprev, const float* __restrict__ hprev,
                                                float* __restrict__ hnext, float* __restrict__ cbuf,
                                                const float4* __restrict__ Wt4b, const float4* __restrict__ bias4,
                                                const float4* __restrict__ biasx, const float4* __restrict__ xW0,
                                                int t0){
  __shared__ __align__(16) float zs[8 * 1024];
  const int tid = threadIdx.x;
  const int jl = tid & 31, ks = tid >> 5;
  const int bid = blockIdx.x;
  const int xcd = bid & 7, idx = bid >> 3;
  const int jt = xcd * 2 + (idx & 1);
  const int bt = idx >> 1;
  const int b0 = bt * 8;
  const int j = jt * 32 + jl;

  for (int i = tid; i < 8 * 256; i += 512){
    int r = i >> 8, c = (i & 255) << 2;
    float4 v;
    if (c < 512){
      if (!t0) v = *(const float4*)&ctxprev[(size_t)(b0 + r) * 512 + c];
      else     v = make_float4(0.f, 0.f, 0.f, 0.f);
    } else {
      v = *(const float4*)&hprev[(size_t)(b0 + r) * 512 + (c - 512)];
    }
    *(float4*)&zs[r * 1024 + c] = v;
  }
  __syncthreads();

  float4 acc[8];
  #pragma unroll
  for (int r = 0; r < 8; r++) acc[r] = make_float4(0.f, 0.f, 0.f, 0.f);

  const int k0 = ks * 64;
  const float4* Wp = Wt4b + (size_t)k0 * 512 + j;
  #pragma unroll 2
  for (int kk = 0; kk < 64; kk += 4){
    float4 w0 = Wp[(size_t)(kk + 0) * 512];
    float4 w1 = Wp[(size_t)(kk + 1) * 512];
    float4 w2 = Wp[(size_t)(kk + 2) * 512];
    float4 w3 = Wp[(size_t)(kk + 3) * 512];
    #pragma unroll
    for (int r = 0; r < 8; r++){
      const float4 xv = *(const float4*)&zs[r * 1024 + k0 + kk];
      acc[r].x += xv.x * w0.x; acc[r].y += xv.x * w0.y; acc[r].z += xv.x * w0.z; acc[r].w += xv.x * w0.w;
      acc[r].x += xv.y * w1.x; acc[r].y += xv.y * w1.y; acc[r].z += xv.y * w1.z; acc[r].w += xv.y * w1.w;
      acc[r].x += xv.z * w2.x; acc[r].y += xv.z * w2.y; acc[r].z += xv.z * w2.z; acc[r].w += xv.z * w2.w;
      acc[r].x += xv.w * w3.x; acc[r].y += xv.w * w3.y; acc[r].z += xv.w * w3.z; acc[r].w += xv.w * w3.w;
    }
  }

  #pragma unroll
  for (int r = 0; r < 8; r++){
    acc[r].x += __shfl_xor(acc[r].x, 32);
    acc[r].y += __shfl_xor(acc[r].y, 32);
    acc[r].z += __shfl_xor(acc[r].z, 32);
    acc[r].w += __shfl_xor(acc[r].w, 32);
  }
  __syncthreads();
  float4* ps = (float4*)zs;
  const int lane = tid & 63, wid = tid >> 6;
  if (lane < 32){
    #pragma unroll
    for (int r = 0; r < 8; r++) ps[(wid * 8 + r) * 32 + lane] = acc[r];
  }
  __syncthreads();

  if (tid < 256){
    const int r = tid >> 5, jj = tid & 31;
    const int j2 = jt * 32 + jj;
    float4 a = ps[r * 32 + jj];
    #pragma unroll
    for (int w = 1; w < 8; w++){
      float4 p = ps[(w * 8 + r) * 32 + jj];
      a.x += p.x; a.y += p.y; a.z += p.z; a.w += p.w;
    }
    const int b = b0 + r;
    float4 bb = bias4[j2];
    float4 bx = t0 ? xW0[(size_t)b * 512 + j2] : biasx[j2];
    float ai = a.x + bb.x + bx.x;
    float af = a.y + bb.y + bx.y;
    float ag = a.z + bb.z + bx.z;
    float ao = a.w + bb.w + bx.w;
    float c_old = cbuf[b * 512 + j2];
    float ig = 1.f / (1.f + __expf(-ai));
    float fg = 1.f / (1.f + __expf(-af));
    float e2 = __expf(2.f * ag);
    float gg = 1.f - 2.f / (e2 + 1.f);
    float og = 1.f / (1.f + __expf(-ao));
    float cn = fg * c_old + ig * gg;
    float ec = __expf(2.f * cn);
    float th = 1.f - 2.f / (ec + 1.f);
    cbuf[b * 512 + j2] = cn;
    hnext[b * 512 + j2] = og * th;
  }
}

__global__ __launch_bounds__(256) void k_attn(const float* __restrict__ hsrc, const float* __restrict__ Wqt,
                                              const float* __restrict__ bq, const u16* __restrict__ Kb,
                                              const u16* __restrict__ Vb, float* __restrict__ attn_out,
                                              float* __restrict__ ctx_t, int t){
  const int bx = blockIdx.x;
  const int b = bx >> 3, nh = bx & 7;
  const int tid = threadIdx.x;
  const int lane = tid & 63, wid = tid >> 6;
  __shared__ float hs[512];
  __shared__ float qred[4][64];
  __shared__ float qs[64];
  __shared__ float sc[512];
  __shared__ float red[16];
  __shared__ float ctxp[4][64];

  hs[tid] = hsrc[b * 512 + tid];
  hs[tid + 256] = hsrc[b * 512 + tid + 256];
  __syncthreads();

  {
    const int d = tid & 63, part = tid >> 6;
    float qa = 0.f;
    const float* wp = Wqt + (size_t)(part * 128) * 512 + nh * 64 + d;
    const float* hp = &hs[part * 128];
    #pragma unroll 8
    for (int k = 0; k < 128; k++)
      qa += hp[k] * wp[(size_t)k * 512];
    qred[part][d] = qa;
  }
  __syncthreads();
  if (tid < 64)
    qs[tid] = (qred[0][tid] + qred[1][tid] + qred[2][tid] + qred[3][tid] + bq[nh * 64 + tid]) * 0.125f;
  __syncthreads();

  const u16* Kp = Kb + (size_t)bx * (512 * 64);
  float s[2];
  #pragma unroll
  for (int ii = 0; ii < 2; ii++){
    int l = tid + ii * 256;
    const u16* kr = Kp + l * 64;
    float acc = 0.f;
    #pragma unroll
    for (int g = 0; g < 8; g++){
      uint4 v = *(const uint4*)(kr + g * 8);
      const float* q8 = qs + g * 8;
      acc += bfbits2f(v.x << 16)          * q8[0];
      acc += bfbits2f(v.x & 0xffff0000u)  * q8[1];
      acc += bfbits2f(v.y << 16)          * q8[2];
      acc += bfbits2f(v.y & 0xffff0000u)  * q8[3];
      acc += bfbits2f(v.z << 16)          * q8[4];
      acc += bfbits2f(v.z & 0xffff0000u)  * q8[5];
      acc += bfbits2f(v.w << 16)          * q8[6];
      acc += bfbits2f(v.w & 0xffff0000u)  * q8[7];
    }
    s[ii] = acc;
  }
  float m = fmaxf(s[0], s[1]);
  for (int off = 32; off > 0; off >>= 1) m = fmaxf(m, __shfl_down(m, off));
  if (lane == 0) red[wid] = m;
  __syncthreads();
  if (tid == 0) red[8] = fmaxf(fmaxf(red[0], red[1]), fmaxf(red[2], red[3]));
  __syncthreads();
  float mx = red[8];
  float e0 = __expf(s[0] - mx), e1 = __expf(s[1] - mx);
  float ps = e0 + e1;
  for (int off = 32; off > 0; off >>= 1) ps += __shfl_down(ps, off);
  if (lane == 0) red[4 + wid] = ps;
  __syncthreads();
  if (tid == 0) red[9] = 1.f / (red[4] + red[5] + red[6] + red[7]);
  __syncthreads();
  float inv = red[9];
  float a0 = e0 * inv, a1 = e1 * inv;
  sc[tid] = a0; sc[tid + 256] = a1;
  float* aout = attn_out + ((size_t)bx * HOR_ + t) * 512;
  aout[tid] = a0; aout[tid + 256] = a1;
  __syncthreads();

  const u16* Vp = Vb + (size_t)bx * (512 * 64);
  const int part = wid;
  const int dg = lane & 31, lh = lane >> 5;
  const int d = dg * 2;
  float c0a = 0.f, c1a = 0.f;
  const u16* vp = Vp + (size_t)(part * 128 + lh) * 64 + d;
  #pragma unroll 8
  for (int i = 0; i < 64; i++){
    int l = part * 128 + i * 2 + lh;
    uint32_t v = *(const uint32_t*)(vp + (size_t)i * 128);
    float w = sc[l];
    c0a += w * bfbits2f(v << 16);
    c1a += w * bfbits2f(v & 0xffff0000u);
  }
  c0a += __shfl_xor(c0a, 32);
  c1a += __shfl_xor(c1a, 32);
  if (lh == 0){ ctxp[part][d] = c0a; ctxp[part][d + 1] = c1a; }
  __syncthreads();
  if (tid < 64)
    ctx_t[(size_t)b * 512 + nh * 64 + tid] = ctxp[0][tid] + ctxp[1][tid] + ctxp[2][tid] + ctxp[3][tid];
}

// batched pred (off critical path): pred[b][t] = ctx_all[t][b] @ Mt + bcomb
__global__ __launch_bounds__(256) void k_pred(const float* __restrict__ ctx_all, const float* __restrict__ Mt,
                                              const float* __restrict__ bcomb, float* __restrict__ outp){
  __shared__ float cs[512];
  __shared__ float pr[4][64];
  const int tid = threadIdx.x;
  const int b = blockIdx.x, t = blockIdx.y;
  const float* cx = ctx_all + ((size_t)t * B_ + b) * 512;
  cs[tid] = cx[tid];
  cs[tid + 256] = cx[tid + 256];
  __syncthreads();
  const int p = tid & 63, part = tid >> 6;
  float acc = 0.f;
  const float* mp = Mt + (size_t)(part * 128) * 64 + p;
  const float* cp = &cs[part * 128];
  #pragma unroll 8
  for (int i = 0; i < 128; i++)
    acc += cp[i] * mp[(size_t)i * 64];
  pr[part][p] = acc;
  __syncthreads();
  if (tid < 64){
    float v = pr[0][tid] + pr[1][tid] + pr[2][tid] + pr[3][tid] + bcomb[tid];
    outp[(size_t)b * (HOR_ * OUT_) + t * OUT_ + tid] = v;
  }
}

// ---------------- host launcher ----------------

extern "C" void kernel_launch(void* const* d_in, const int* in_sizes, int n_in,
                              void* d_out, int out_size, void* d_ws, size_t ws_size,
                              hipStream_t stream){
  const float* enc  = (const float*)d_in[0];
  const float* h0   = (const float*)d_in[1];
  const float* c0   = (const float*)d_in[2];
  const float* dec  = (const float*)d_in[3];
  const float* W_ih = (const float*)d_in[4];
  const float* W_hh = (const float*)d_in[5];
  const float* b_ih = (const float*)d_in[6];
  const float* b_hh = (const float*)d_in[7];
  const float* Wq   = (const float*)d_in[8];
  const float* bq   = (const float*)d_in[9];
  const float* Wk   = (const float*)d_in[10];
  const float* bk   = (const float*)d_in[11];
  const float* Wv   = (const float*)d_in[12];
  const float* bv   = (const float*)d_in[13];
  const float* Wo   = (const float*)d_in[14];
  const float* bo   = (const float*)d_in[15];
  const float* Wfc  = (const float*)d_in[16];
  const float* bfc  = (const float*)d_in[17];
  float* out = (float*)d_out;

  char* ws = (char*)d_ws;
  size_t off = 0;
  auto alloc = [&](size_t bytes){ void* p = ws + off; off += (bytes + 255) & ~(size_t)255; return p; };
  u16*   Xb    = (u16*)  alloc((size_t)B_ * L_ * H_ * 2);
  u16*   Kb    = (u16*)  alloc((size_t)B_ * NH_ * L_ * HD_ * 2);
  u16*   Vb    = (u16*)  alloc((size_t)B_ * NH_ * L_ * HD_ * 2);
  u16*   Wkv   = (u16*)  alloc((size_t)1024 * 512 * 2);
  float* Wt4b  = (float*)alloc((size_t)1024 * 512 * 4 * 4);   // [k][j][4 gates]
  float* Wqt   = (float*)alloc((size_t)512 * 512 * 4);
  float* Mt    = (float*)alloc((size_t)512 * 64 * 4);
  float* bcomb = (float*)alloc(64 * 4);
  float* bias4 = (float*)alloc((size_t)2048 * 4);
  float* biasx = (float*)alloc((size_t)2048 * 4);
  float* xW0   = (float*)alloc((size_t)B_ * 2048 * 4);
  float* hb0   = (float*)alloc((size_t)B_ * H_ * 4);
  float* hb1   = (float*)alloc((size_t)B_ * H_ * 4);
  float* cbuf  = (float*)alloc((size_t)B_ * H_ * 4);
  float* ctx_all = (float*)Xb;                // aliases Xb (dead after k_gemm_kv)
  if (off > ws_size){
    fprintf(stderr, "WORKSPACE TOO SMALL: need %zu, have %zu\n", off, ws_size);
  }

  float* out_pred = out;                                 // (B, HOR, OUT)
  float* out_attn = out + (size_t)B_ * HOR_ * OUT_;      // (B, NH, HOR, L)

  k_convert_x<<<4096, 256, 0, stream>>>((const float4*)enc, (ushort4*)Xb, (B_ * L_ * H_) / 4);
  k_prep<<<7945, 256, 0, stream>>>(Wk, Wv, W_ih, W_hh, b_ih, b_hh, Wq, Wfc, Wo, bo, bfc,
                                   dec, h0, c0, Wkv, Wt4b, Wqt, bias4, Mt, bcomb, xW0, hb0, cbuf);
  k_gemm_kv<<<dim3(8, 512), 256, 0, stream>>>(Xb, Wkv, bk, bv, Kb, Vb);
  k_prep2<<<4097, 256, 0, stream>>>(Mt, W_ih, bcomb, Wt4b, biasx);

  // decide coop path once (host-side queries only; no stream ops)
  static int coop_ok = -1;
  if (coop_ok < 0){
    int dev = 0;
    (void)hipGetDevice(&dev);
    int attr = 0;
    (void)hipDeviceGetAttribute(&attr, hipDeviceAttributeCooperativeLaunch, dev);
    int occ = 0;
    (void)hipOccupancyMaxActiveBlocksPerMultiprocessor(&occ, k_loop, 256, 0);
    coop_ok = (attr != 0 && occ >= 4) ? 1 : 0;
  }

  bool did_coop = false;
  if (coop_ok == 1){
    const float* Wqt_c = Wqt; const float* bq_c = bq;
    const u16* Kb_c = Kb; const u16* Vb_c = Vb;
    const float4* Wt4b_c = (const float4*)Wt4b;
    const float4* bias4_c = (const float4*)bias4;
    const float4* biasx_c = (const float4*)biasx;
    const float4* xW0_c = (const float4*)xW0;
    float* hb0_c = hb0; float* hb1_c = hb1; float* cbuf_c = cbuf;
    float* ctx_c = ctx_all; float* aout_c = out_attn;
    void* args[] = { &Wqt_c, &bq_c, &Kb_c, &Vb_c, &Wt4b_c, &bias4_c, &biasx_c, &xW0_c,
                     &hb0_c, &hb1_c, &cbuf_c, &ctx_c, &aout_c };
    hipError_t e = hipLaunchCooperativeKernel((const void*)k_loop, dim3(1024), dim3(256),
                                              args, 0, stream);
    if (e == hipSuccess) did_coop = true;
  }

  if (!did_coop){
    float* hb[2] = {hb0, hb1};
    for (int t = 0; t < HOR_; t++){
      const float* cprev = (t == 0) ? nullptr : (ctx_all + (size_t)(t - 1) * B_ * H_);
      k_gates2<<<256, 512, 0, stream>>>(cprev, hb[t & 1], hb[(t + 1) & 1], cbuf,
                                        (const float4*)Wt4b, (const float4*)bias4,
                                        (const float4*)biasx, (const float4*)xW0, t == 0 ? 1 : 0);
      k_attn<<<1024, 256, 0, stream>>>(hb[(t + 1) & 1], Wqt, bq, Kb, Vb, out_attn,
                                       ctx_all + (size_t)t * B_ * H_, t);
    }
  }
  k_pred<<<dim3(128, 24), 256, 0, stream>>>(ctx_all, Mt, bcomb, out_pred);
}

// Round 4
// 1746.989 us; speedup vs baseline: 1.2425x; 1.0708x over previous
//
#include <hip/hip_runtime.h>
#include <cstdio>
#include <cstdint>

#define B_   128
#define L_   512
#define H_   512
#define IN_  64
#define OUT_ 64
#define NH_  8
#define HD_  64
#define HOR_ 24

typedef unsigned short u16;
typedef __attribute__((ext_vector_type(8))) __bf16 bf16x8;
typedef __attribute__((ext_vector_type(4))) float f32x4;

__device__ __forceinline__ float bfbits2f(uint32_t hi){ union { uint32_t u; float f; } v; v.u = hi; return v.f; }
__device__ __forceinline__ u16 f2bf(float f){
  union { uint32_t u; float f2; } v; v.f2 = f;
  uint32_t x = v.u;
  return (u16)((x + 0x7FFFu + ((x >> 16) & 1u)) >> 16);  // RNE
}

// ---------------- one-time prep ----------------

__global__ __launch_bounds__(256) void k_convert_x(const float4* __restrict__ X, ushort4* __restrict__ Xb, int n4){
  int i = blockIdx.x * blockDim.x + threadIdx.x;
  int stride = gridDim.x * blockDim.x;
  for (; i < n4; i += stride){
    float4 v = X[i];
    ushort4 o;
    o.x = f2bf(v.x); o.y = f2bf(v.y); o.z = f2bf(v.z); o.w = f2bf(v.w);
    Xb[i] = o;
  }
}

// fused small prep: block ranges (see comments inline)
__global__ __launch_bounds__(256) void k_prep(const float* __restrict__ Wk, const float* __restrict__ Wv,
                                              const float* __restrict__ W_ih, const float* __restrict__ W_hh,
                                              const float* __restrict__ b_ih, const float* __restrict__ b_hh,
                                              const float* __restrict__ Wq, const float* __restrict__ Wfc,
                                              const float* __restrict__ Wo, const float* __restrict__ bo,
                                              const float* __restrict__ bfc, const float* __restrict__ dec,
                                              const float* __restrict__ h0, const float* __restrict__ c0,
                                              u16* __restrict__ Wkv, float* __restrict__ Wt4b,
                                              float* __restrict__ Wqt, float* __restrict__ bias4,
                                              float* __restrict__ Mt, float* __restrict__ bcomb,
                                              float* __restrict__ xW0, float* __restrict__ hb0,
                                              float* __restrict__ cbuf){
  const int bid = blockIdx.x, tid = threadIdx.x;
  if (bid < 129){
    int i = bid * 256 + tid;
    if (i < 32768){
      int p = i >> 9, d = i & 511;
      float acc = 0.f;
      #pragma unroll 4
      for (int j = 0; j < 512; j++) acc += Wfc[p * 512 + j] * Wo[j * 512 + d];
      Mt[d * 64 + p] = acc;
    } else if (i < 32832){
      int p = i - 32768;
      float acc = bfc[p];
      for (int j = 0; j < 512; j++) acc += Wfc[p * 512 + j] * bo[j];
      bcomb[p] = acc;
    }
  } else if (bid < 2177){
    int i = (bid - 129) * 256 + tid;           // 1024*512
    int n = i >> 9;
    Wkv[i] = f2bf(n < 512 ? Wk[i] : Wv[i - 262144]);
  } else if (bid < 6273){
    int i = (bid - 2177) * 256 + tid;          // 512*512*4 -> W_hh into rows [512,1024)
    int kh = i >> 11, rem = i & 2047;
    int j = rem >> 2, g = rem & 3;
    Wt4b[((size_t)(512 + kh) * 512 + j) * 4 + g] = W_hh[(size_t)(g * 512 + j) * 512 + kh];
  } else if (bid < 7297){
    int i = (bid - 6273) * 256 + tid;          // 512*512
    int k = i >> 9, n = i & 511;
    Wqt[i] = Wq[n * 512 + k];
  } else if (bid < 7305){
    int i = (bid - 7297) * 256 + tid;          // 2048
    int j = i >> 2, g = i & 3;
    bias4[i] = b_ih[g * 512 + j] + b_hh[g * 512 + j];
  } else if (bid < 7433){
    // xW0[b][j*4+g] = sum_p dec[b][p] * W_ih[g*512+j][p]  (t=0 x-contribution)
    __shared__ float dv[64];
    int b = bid - 7305;
    if (tid < 64) dv[tid] = dec[b * 64 + tid];
    __syncthreads();
    #pragma unroll
    for (int q = 0; q < 8; q++){
      int o = tid * 8 + q;                     // 0..2047
      int j = o >> 2, g = o & 3;
      const float* wr = W_ih + (size_t)(g * 512 + j) * 64;
      float acc = 0.f;
      #pragma unroll
      for (int p = 0; p < 64; p += 4)
        acc += dv[p] * wr[p] + dv[p+1] * wr[p+1] + dv[p+2] * wr[p+2] + dv[p+3] * wr[p+3];
      xW0[(size_t)b * 2048 + o] = acc;
    }
  } else {
    int i = (bid - 7433) * 256 + tid;          // 65536 + 65536
    if (i < 65536) cbuf[i] = c0[i];
    else hb0[i - 65536] = h0[i - 65536];
  }
}

// prep2 (needs Mt, bcomb from k_prep)
__global__ __launch_bounds__(256) void k_prep2(const float* __restrict__ Mt, const float* __restrict__ W_ih,
                                               const float* __restrict__ bcomb, float* __restrict__ Wt4b,
                                               float* __restrict__ biasx){
  const int bid = blockIdx.x, tid = threadIdx.x;
  if (bid < 4096){
    int i = bid * 256 + tid;                   // 512*2048
    int k = i >> 11, gcol = i & 2047;
    const float4* mr = (const float4*)(Mt + (size_t)k * 64);
    const float4* wr = (const float4*)(W_ih + (size_t)gcol * 64);
    float acc = 0.f;
    #pragma unroll
    for (int p = 0; p < 16; p++){
      float4 m = mr[p], w = wr[p];
      acc += m.x * w.x + m.y * w.y + m.z * w.z + m.w * w.w;
    }
    int g = gcol >> 9, j = gcol & 511;
    Wt4b[((size_t)k * 512 + j) * 4 + g] = acc;
  } else {
    #pragma unroll
    for (int q = 0; q < 8; q++){
      int o = tid * 8 + q;
      int j = o >> 2, g = o & 3;
      const float4* br = (const float4*)bcomb;
      const float4* wr = (const float4*)(W_ih + (size_t)(g * 512 + j) * 64);
      float acc = 0.f;
      #pragma unroll
      for (int p = 0; p < 16; p++){
        float4 b4 = br[p], w = wr[p];
        acc += b4.x * w.x + b4.y * w.y + b4.z * w.z + b4.w * w.w;
      }
      biasx[o] = acc;
    }
  }
}

// ---------------- K/V projection (bf16 MFMA GEMM, XCD-banded) ----------------
__global__ __launch_bounds__(256) void k_gemm_kv(const u16* __restrict__ Xb, const u16* __restrict__ Wkv,
                                                 const float* __restrict__ bk, const float* __restrict__ bv,
                                                 u16* __restrict__ Kb, u16* __restrict__ Vb){
  __shared__ __align__(16) u16 As[128 * 64];
  __shared__ __align__(16) u16 Bs[128 * 64];
  const int tid = threadIdx.x;
  const int lane = tid & 63, wid = tid >> 6;
  const int wm = wid >> 1, wn = wid & 1;
  const int mt = blockIdx.x * 64 + (blockIdx.y >> 3);
  const int nt = blockIdx.y & 7;
  const int n0 = nt * 128, m0 = mt * 128;

  f32x4 zero = {0.f, 0.f, 0.f, 0.f};
  f32x4 acc[4][4];
  #pragma unroll
  for (int i = 0; i < 4; i++)
    #pragma unroll
    for (int j = 0; j < 4; j++) acc[i][j] = zero;

  for (int kt = 0; kt < 512; kt += 64){
    #pragma unroll
    for (int s = 0; s < 4; s++){
      int slot = tid + 256 * s;                // 0..1023
      int r = slot >> 3, cg = slot & 7;
      int sw = (cg ^ (r & 7)) << 3;
      *(uint4*)&As[r * 64 + sw] = *(const uint4*)&Xb[(size_t)(m0 + r) * 512 + kt + cg * 8];
      *(uint4*)&Bs[r * 64 + sw] = *(const uint4*)&Wkv[(size_t)(n0 + r) * 512 + kt + cg * 8];
    }
    __syncthreads();
    #pragma unroll
    for (int ks = 0; ks < 2; ks++){
      bf16x8 af[4], bfr[4];
      int g = ks * 4 + (lane >> 4);
      int ra = wm * 64 + (lane & 15);
      int rb = wn * 64 + (lane & 15);
      #pragma unroll
      for (int i = 0; i < 4; i++){
        int r = ra + i * 16;
        af[i] = *(const bf16x8*)&As[r * 64 + ((g ^ (r & 7)) << 3)];
      }
      #pragma unroll
      for (int j = 0; j < 4; j++){
        int r = rb + j * 16;
        bfr[j] = *(const bf16x8*)&Bs[r * 64 + ((g ^ (r & 7)) << 3)];
      }
      #pragma unroll
      for (int i = 0; i < 4; i++)
        #pragma unroll
        for (int j = 0; j < 4; j++)
          acc[i][j] = __builtin_amdgcn_mfma_f32_16x16x32_bf16(af[i], bfr[j], acc[i][j], 0, 0, 0);
    }
    __syncthreads();
  }

  #pragma unroll
  for (int j = 0; j < 4; j++){
    int n = n0 + wn * 64 + j * 16 + (lane & 15);
    float bias = (n < 512) ? bk[n] : bv[n - 512];
    u16* dst = (n < 512) ? Kb : Vb;
    int nh = (n >> 6) & 7, hd = n & 63;
    #pragma unroll
    for (int i = 0; i < 4; i++){
      #pragma unroll
      for (int r = 0; r < 4; r++){
        int m = m0 + wm * 64 + i * 16 + (lane >> 4) * 4 + r;
        int b = m >> 9, l = m & 511;
        float val = acc[i][j][r] + bias;
        dst[((size_t)((b * 8 + nh) * 512 + l)) * 64 + hd] = f2bf(val);
      }
    }
  }
}

// ---------------- per-step kernels ----------------

// gates GEMM 128 x 2048 x K=1024 over z=[ctx_{t-1}, h_{t-1}] + LSTM + partial q.
// 512 thr = 32 j x 16 ksplit; 8 b-rows register-blocked. After the LSTM epilogue
// the block's h-slice (8 b x 32 j) is staged in LDS and each block computes its
// slice's contribution to q = h @ Wqt (all 512 q-cols) into qp[jt][b][512].
// This removes the q-projection phase from the attention kernel.
__global__ __launch_bounds__(512) void k_gates3(const float* __restrict__ ctxprev, const float* __restrict__ hprev,
                                                float* __restrict__ hnext, float* __restrict__ cbuf,
                                                const float4* __restrict__ Wt4b, const float4* __restrict__ bias4,
                                                const float4* __restrict__ biasx, const float4* __restrict__ xW0,
                                                const float* __restrict__ Wqt, float* __restrict__ qp,
                                                int t0){
  __shared__ __align__(16) float zs[8 * 1024 + 256];   // 32 KB z/psum + 1 KB h-stage
  const int tid = threadIdx.x;
  const int jl = tid & 31, ks = tid >> 5;
  // XCD swizzle: same-jt blocks (sharing the W slice) colocate per XCD.
  const int bid = blockIdx.x;                          // 256 blocks
  const int xcd = bid & 7, idx = bid >> 3;
  const int jt = xcd * 2 + (idx & 1);
  const int bt = idx >> 1;
  const int b0 = bt * 8;
  const int j = jt * 32 + jl;

  // stage z = [ctx(512), h(512)] for 8 b-rows
  for (int i = tid; i < 8 * 256; i += 512){
    int r = i >> 8, c = (i & 255) << 2;
    float4 v;
    if (c < 512){
      if (!t0) v = *(const float4*)&ctxprev[(size_t)(b0 + r) * 512 + c];
      else     v = make_float4(0.f, 0.f, 0.f, 0.f);
    } else {
      v = *(const float4*)&hprev[(size_t)(b0 + r) * 512 + (c - 512)];
    }
    *(float4*)&zs[r * 1024 + c] = v;
  }
  __syncthreads();

  float4 acc[8];
  #pragma unroll
  for (int r = 0; r < 8; r++) acc[r] = make_float4(0.f, 0.f, 0.f, 0.f);

  const int k0 = ks * 64;
  const float4* Wp = Wt4b + (size_t)k0 * 512 + j;
  #pragma unroll 2
  for (int kk = 0; kk < 64; kk += 4){
    float4 w0 = Wp[(size_t)(kk + 0) * 512];
    float4 w1 = Wp[(size_t)(kk + 1) * 512];
    float4 w2 = Wp[(size_t)(kk + 2) * 512];
    float4 w3 = Wp[(size_t)(kk + 3) * 512];
    #pragma unroll
    for (int r = 0; r < 8; r++){
      const float4 xv = *(const float4*)&zs[r * 1024 + k0 + kk];
      acc[r].x += xv.x * w0.x; acc[r].y += xv.x * w0.y; acc[r].z += xv.x * w0.z; acc[r].w += xv.x * w0.w;
      acc[r].x += xv.y * w1.x; acc[r].y += xv.y * w1.y; acc[r].z += xv.y * w1.z; acc[r].w += xv.y * w1.w;
      acc[r].x += xv.z * w2.x; acc[r].y += xv.z * w2.y; acc[r].z += xv.z * w2.z; acc[r].w += xv.z * w2.w;
      acc[r].x += xv.w * w3.x; acc[r].y += xv.w * w3.y; acc[r].z += xv.w * w3.z; acc[r].w += xv.w * w3.w;
    }
  }

  // combine ks pairs within the wave, then 8 wave-partials via LDS
  #pragma unroll
  for (int r = 0; r < 8; r++){
    acc[r].x += __shfl_xor(acc[r].x, 32);
    acc[r].y += __shfl_xor(acc[r].y, 32);
    acc[r].z += __shfl_xor(acc[r].z, 32);
    acc[r].w += __shfl_xor(acc[r].w, 32);
  }
  __syncthreads();                                     // zs reads done; reuse as psum
  float4* ps = (float4*)zs;
  const int lane = tid & 63, wid = tid >> 6;
  if (lane < 32){
    #pragma unroll
    for (int r = 0; r < 8; r++) ps[(wid * 8 + r) * 32 + lane] = acc[r];
  }
  __syncthreads();

  if (tid < 256){
    const int r = tid >> 5, jj = tid & 31;
    const int j2 = jt * 32 + jj;
    float4 a = ps[r * 32 + jj];
    #pragma unroll
    for (int w = 1; w < 8; w++){
      float4 p = ps[(w * 8 + r) * 32 + jj];
      a.x += p.x; a.y += p.y; a.z += p.z; a.w += p.w;
    }
    const int b = b0 + r;
    float4 bb = bias4[j2];
    float4 bx = t0 ? xW0[(size_t)b * 512 + j2] : biasx[j2];
    float ai = a.x + bb.x + bx.x;
    float af = a.y + bb.y + bx.y;
    float ag = a.z + bb.z + bx.z;
    float ao = a.w + bb.w + bx.w;
    float c_old = cbuf[b * 512 + j2];
    float ig = 1.f / (1.f + __expf(-ai));
    float fg = 1.f / (1.f + __expf(-af));
    float e2 = __expf(2.f * ag);
    float gg = 1.f - 2.f / (e2 + 1.f);
    float og = 1.f / (1.f + __expf(-ao));
    float cn = fg * c_old + ig * gg;
    float ec = __expf(2.f * cn);
    float th = 1.f - 2.f / (ec + 1.f);
    cbuf[b * 512 + j2] = cn;
    float hv = og * th;
    hnext[b * 512 + j2] = hv;
    zs[8192 + tid] = hv;                               // h-stage (disjoint from psum)
  }
  __syncthreads();

  // partial q: qp[jt][b0+r][col] = sum_{j<32} h[r][j] * Wqt[jt*32+j][col]
  {
    const int r = tid >> 6, cg = tid & 63;             // 8 b-rows x 64 col-groups
    float4 f0 = make_float4(0.f, 0.f, 0.f, 0.f);
    float4 f1 = make_float4(0.f, 0.f, 0.f, 0.f);
    const float* wq = Wqt + (size_t)(jt * 32) * 512 + cg * 8;
    const float* hv = &zs[8192 + r * 32];
    #pragma unroll 8
    for (int jj = 0; jj < 32; jj++){
      float h = hv[jj];
      const float4* w = (const float4*)(wq + (size_t)jj * 512);
      float4 w0 = w[0], w1 = w[1];
      f0.x += h * w0.x; f0.y += h * w0.y; f0.z += h * w0.z; f0.w += h * w0.w;
      f1.x += h * w1.x; f1.y += h * w1.y; f1.z += h * w1.z; f1.w += h * w1.w;
    }
    float* qpo = qp + ((size_t)jt * 128 + b0 + r) * 512 + cg * 8;
    *(float4*)qpo = f0;
    *(float4*)(qpo + 4) = f1;
  }
}

// attention: one block per (b,nh). q arrives as 16 partials in qp; no h read,
// no q-projection phase. scores (K stream) -> softmax -> ctx (V stream, uint2).
__global__ __launch_bounds__(256) void k_attn2(const float* __restrict__ qp, const float* __restrict__ bq,
                                               const u16* __restrict__ Kb, const u16* __restrict__ Vb,
                                               float* __restrict__ attn_out, float* __restrict__ ctx_t, int t){
  const int bx = blockIdx.x;
  const int b = bx >> 3, nh = bx & 7;
  const int tid = threadIdx.x;
  const int lane = tid & 63, wid = tid >> 6;
  __shared__ float qs[64];
  __shared__ float sc[512];
  __shared__ float red[16];
  __shared__ __align__(16) float ctxp[4][64];

  if (tid < 64){
    float sum = bq[nh * 64 + tid];
    #pragma unroll
    for (int s = 0; s < 16; s++)
      sum += qp[((size_t)s * 128 + b) * 512 + nh * 64 + tid];
    qs[tid] = sum * 0.125f;                            // fold 1/sqrt(HD)
  }
  __syncthreads();

  const u16* Kp = Kb + (size_t)bx * (512 * 64);
  float s0 = 0.f, s1 = 0.f;
  {
    const u16* kr0p = Kp + (size_t)tid * 64;
    const u16* kr1p = Kp + (size_t)(tid + 256) * 64;
    #pragma unroll
    for (int g = 0; g < 8; g++){
      const float* q8 = qs + g * 8;
      uint4 v = *(const uint4*)(kr0p + g * 8);
      s0 += bfbits2f(v.x << 16)          * q8[0];
      s0 += bfbits2f(v.x & 0xffff0000u)  * q8[1];
      s0 += bfbits2f(v.y << 16)          * q8[2];
      s0 += bfbits2f(v.y & 0xffff0000u)  * q8[3];
      s0 += bfbits2f(v.z << 16)          * q8[4];
      s0 += bfbits2f(v.z & 0xffff0000u)  * q8[5];
      s0 += bfbits2f(v.w << 16)          * q8[6];
      s0 += bfbits2f(v.w & 0xffff0000u)  * q8[7];
      uint4 w = *(const uint4*)(kr1p + g * 8);
      s1 += bfbits2f(w.x << 16)          * q8[0];
      s1 += bfbits2f(w.x & 0xffff0000u)  * q8[1];
      s1 += bfbits2f(w.y << 16)          * q8[2];
      s1 += bfbits2f(w.y & 0xffff0000u)  * q8[3];
      s1 += bfbits2f(w.z << 16)          * q8[4];
      s1 += bfbits2f(w.z & 0xffff0000u)  * q8[5];
      s1 += bfbits2f(w.w << 16)          * q8[6];
      s1 += bfbits2f(w.w & 0xffff0000u)  * q8[7];
    }
  }
  float m = fmaxf(s0, s1);
  for (int off = 32; off > 0; off >>= 1) m = fmaxf(m, __shfl_down(m, off));
  if (lane == 0) red[wid] = m;
  __syncthreads();
  if (tid == 0) red[8] = fmaxf(fmaxf(red[0], red[1]), fmaxf(red[2], red[3]));
  __syncthreads();
  float mx = red[8];
  float e0 = __expf(s0 - mx), e1 = __expf(s1 - mx);
  float psum = e0 + e1;
  for (int off = 32; off > 0; off >>= 1) psum += __shfl_down(psum, off);
  if (lane == 0) red[4 + wid] = psum;
  __syncthreads();
  if (tid == 0) red[9] = 1.f / (red[4] + red[5] + red[6] + red[7]);
  __syncthreads();
  float inv = red[9];
  float a0 = e0 * inv, a1 = e1 * inv;
  sc[tid] = a0; sc[tid + 256] = a1;
  float* aout = attn_out + ((size_t)bx * HOR_ + t) * 512;
  aout[tid] = a0; aout[tid + 256] = a1;
  __syncthreads();

  // ctx: wave part covers 128 l; lane = (lq 4-rows, dq 16 d-quads); uint2 loads.
  const int part = wid;
  const int dq = lane & 15, lq = lane >> 4;
  float4 cacc = make_float4(0.f, 0.f, 0.f, 0.f);
  const u16* vp = Vb + (size_t)bx * (512 * 64) + (size_t)(part * 128 + lq) * 64 + dq * 4;
  #pragma unroll 8
  for (int i = 0; i < 32; i++){
    int l = part * 128 + i * 4 + lq;
    uint2 v = *(const uint2*)(vp + (size_t)i * 256);
    float w = sc[l];
    cacc.x += w * bfbits2f(v.x << 16);
    cacc.y += w * bfbits2f(v.x & 0xffff0000u);
    cacc.z += w * bfbits2f(v.y << 16);
    cacc.w += w * bfbits2f(v.y & 0xffff0000u);
  }
  cacc.x += __shfl_xor(cacc.x, 16); cacc.y += __shfl_xor(cacc.y, 16);
  cacc.z += __shfl_xor(cacc.z, 16); cacc.w += __shfl_xor(cacc.w, 16);
  cacc.x += __shfl_xor(cacc.x, 32); cacc.y += __shfl_xor(cacc.y, 32);
  cacc.z += __shfl_xor(cacc.z, 32); cacc.w += __shfl_xor(cacc.w, 32);
  if (lq == 0) *(float4*)&ctxp[part][dq * 4] = cacc;
  __syncthreads();
  if (tid < 64)
    ctx_t[(size_t)b * 512 + nh * 64 + tid] = ctxp[0][tid] + ctxp[1][tid] + ctxp[2][tid] + ctxp[3][tid];
}

// batched pred (off critical path): pred[b][t] = ctx_all[t][b] @ Mt + bcomb
__global__ __launch_bounds__(256) void k_pred(const float* __restrict__ ctx_all, const float* __restrict__ Mt,
                                              const float* __restrict__ bcomb, float* __restrict__ outp){
  __shared__ float cs[512];
  __shared__ float pr[4][64];
  const int tid = threadIdx.x;
  const int b = blockIdx.x, t = blockIdx.y;
  const float* cx = ctx_all + ((size_t)t * B_ + b) * 512;
  cs[tid] = cx[tid];
  cs[tid + 256] = cx[tid + 256];
  __syncthreads();
  const int p = tid & 63, part = tid >> 6;
  float acc = 0.f;
  const float* mp = Mt + (size_t)(part * 128) * 64 + p;
  const float* cp = &cs[part * 128];
  #pragma unroll 8
  for (int i = 0; i < 128; i++)
    acc += cp[i] * mp[(size_t)i * 64];
  pr[part][p] = acc;
  __syncthreads();
  if (tid < 64){
    float v = pr[0][tid] + pr[1][tid] + pr[2][tid] + pr[3][tid] + bcomb[tid];
    outp[(size_t)b * (HOR_ * OUT_) + t * OUT_ + tid] = v;
  }
}

// ---------------- host launcher ----------------

extern "C" void kernel_launch(void* const* d_in, const int* in_sizes, int n_in,
                              void* d_out, int out_size, void* d_ws, size_t ws_size,
                              hipStream_t stream){
  const float* enc  = (const float*)d_in[0];
  const float* h0   = (const float*)d_in[1];
  const float* c0   = (const float*)d_in[2];
  const float* dec  = (const float*)d_in[3];
  const float* W_ih = (const float*)d_in[4];
  const float* W_hh = (const float*)d_in[5];
  const float* b_ih = (const float*)d_in[6];
  const float* b_hh = (const float*)d_in[7];
  const float* Wq   = (const float*)d_in[8];
  const float* bq   = (const float*)d_in[9];
  const float* Wk   = (const float*)d_in[10];
  const float* bk   = (const float*)d_in[11];
  const float* Wv   = (const float*)d_in[12];
  const float* bv   = (const float*)d_in[13];
  const float* Wo   = (const float*)d_in[14];
  const float* bo   = (const float*)d_in[15];
  const float* Wfc  = (const float*)d_in[16];
  const float* bfc  = (const float*)d_in[17];
  float* out = (float*)d_out;

  char* ws = (char*)d_ws;
  size_t off = 0;
  auto alloc = [&](size_t bytes){ void* p = ws + off; off += (bytes + 255) & ~(size_t)255; return p; };
  u16*   Xb    = (u16*)  alloc((size_t)B_ * L_ * H_ * 2);
  u16*   Kb    = (u16*)  alloc((size_t)B_ * NH_ * L_ * HD_ * 2);
  u16*   Vb    = (u16*)  alloc((size_t)B_ * NH_ * L_ * HD_ * 2);
  u16*   Wkv   = (u16*)  alloc((size_t)1024 * 512 * 2);
  float* Wt4b  = (float*)alloc((size_t)1024 * 512 * 4 * 4);   // [k][j][4 gates]
  float* Wqt   = (float*)alloc((size_t)512 * 512 * 4);
  float* Mt    = (float*)alloc((size_t)512 * 64 * 4);
  float* bcomb = (float*)alloc(64 * 4);
  float* bias4 = (float*)alloc((size_t)2048 * 4);
  float* biasx = (float*)alloc((size_t)2048 * 4);
  float* xW0   = (float*)alloc((size_t)B_ * 2048 * 4);
  float* hb0   = (float*)alloc((size_t)B_ * H_ * 4);
  float* hb1   = (float*)alloc((size_t)B_ * H_ * 4);
  float* cbuf  = (float*)alloc((size_t)B_ * H_ * 4);
  float* qp    = (float*)alloc((size_t)16 * B_ * 512 * 4);    // 16 jt-partials of q
  float* ctx_all = (float*)Xb;                // aliases Xb (dead after k_gemm_kv)
  if (off > ws_size){
    fprintf(stderr, "WORKSPACE TOO SMALL: need %zu, have %zu\n", off, ws_size);
  }

  float* out_pred = out;                                 // (B, HOR, OUT)
  float* out_attn = out + (size_t)B_ * HOR_ * OUT_;      // (B, NH, HOR, L)

  k_convert_x<<<4096, 256, 0, stream>>>((const float4*)enc, (ushort4*)Xb, (B_ * L_ * H_) / 4);
  k_prep<<<7945, 256, 0, stream>>>(Wk, Wv, W_ih, W_hh, b_ih, b_hh, Wq, Wfc, Wo, bo, bfc,
                                   dec, h0, c0, Wkv, Wt4b, Wqt, bias4, Mt, bcomb, xW0, hb0, cbuf);
  k_gemm_kv<<<dim3(8, 512), 256, 0, stream>>>(Xb, Wkv, bk, bv, Kb, Vb);
  k_prep2<<<4097, 256, 0, stream>>>(Mt, W_ih, bcomb, Wt4b, biasx);

  float* hb[2] = {hb0, hb1};
  for (int t = 0; t < HOR_; t++){
    const float* cprev = (t == 0) ? nullptr : (ctx_all + (size_t)(t - 1) * B_ * H_);
    k_gates3<<<256, 512, 0, stream>>>(cprev, hb[t & 1], hb[(t + 1) & 1], cbuf,
                                      (const float4*)Wt4b, (const float4*)bias4,
                                      (const float4*)biasx, (const float4*)xW0,
                                      Wqt, qp, t == 0 ? 1 : 0);
    k_attn2<<<1024, 256, 0, stream>>>(qp, bq, Kb, Vb, out_attn,
                                      ctx_all + (size_t)t * B_ * H_, t);
  }
  k_pred<<<dim3(128, 24), 256, 0, stream>>>(ctx_all, Mt, bcomb, out_pred);
}

// Round 6
// 1475.812 us; speedup vs baseline: 1.4708x; 1.1837x over previous
//
#include <hip/hip_runtime.h>
#include <cstdio>
#include <cstdint>

#define B_   128
#define L_   512
#define H_   512
#define IN_  64
#define OUT_ 64
#define NH_  8
#define HD_  64
#define HOR_ 24

typedef unsigned short u16;
typedef __attribute__((ext_vector_type(8))) __bf16 bf16x8;
typedef __attribute__((ext_vector_type(4))) float f32x4;

__device__ __forceinline__ float bfbits2f(uint32_t hi){ union { uint32_t u; float f; } v; v.u = hi; return v.f; }
__device__ __forceinline__ u16 f2bf(float f){
  union { uint32_t u; float f2; } v; v.f2 = f;
  uint32_t x = v.u;
  return (u16)((x + 0x7FFFu + ((x >> 16) & 1u)) >> 16);  // RNE
}

// ---------------- one-time prep ----------------

__global__ __launch_bounds__(256) void k_convert_x(const float4* __restrict__ X, ushort4* __restrict__ Xb, int n4){
  int i = blockIdx.x * blockDim.x + threadIdx.x;
  int stride = gridDim.x * blockDim.x;
  for (; i < n4; i += stride){
    float4 v = X[i];
    ushort4 o;
    o.x = f2bf(v.x); o.y = f2bf(v.y); o.z = f2bf(v.z); o.w = f2bf(v.w);
    Xb[i] = o;
  }
}

// fused small prep: block ranges (see comments inline)
__global__ __launch_bounds__(256) void k_prep(const float* __restrict__ Wk, const float* __restrict__ Wv,
                                              const float* __restrict__ W_ih, const float* __restrict__ W_hh,
                                              const float* __restrict__ b_ih, const float* __restrict__ b_hh,
                                              const float* __restrict__ Wq, const float* __restrict__ Wfc,
                                              const float* __restrict__ Wo, const float* __restrict__ bo,
                                              const float* __restrict__ bfc, const float* __restrict__ dec,
                                              const float* __restrict__ h0, const float* __restrict__ c0,
                                              u16* __restrict__ Wkv, float* __restrict__ Wt4b,
                                              float* __restrict__ Wqt, float* __restrict__ bias4,
                                              float* __restrict__ Mt, float* __restrict__ bcomb,
                                              float* __restrict__ xW0, float* __restrict__ hb0,
                                              float* __restrict__ cbuf){
  const int bid = blockIdx.x, tid = threadIdx.x;
  if (bid < 129){
    int i = bid * 256 + tid;
    if (i < 32768){
      int p = i >> 9, d = i & 511;
      float acc = 0.f;
      #pragma unroll 4
      for (int j = 0; j < 512; j++) acc += Wfc[p * 512 + j] * Wo[j * 512 + d];
      Mt[d * 64 + p] = acc;
    } else if (i < 32832){
      int p = i - 32768;
      float acc = bfc[p];
      for (int j = 0; j < 512; j++) acc += Wfc[p * 512 + j] * bo[j];
      bcomb[p] = acc;
    }
  } else if (bid < 2177){
    int i = (bid - 129) * 256 + tid;           // 1024*512
    int n = i >> 9;
    Wkv[i] = f2bf(n < 512 ? Wk[i] : Wv[i - 262144]);
  } else if (bid < 6273){
    int i = (bid - 2177) * 256 + tid;          // 512*512*4 -> W_hh into rows [512,1024)
    int kh = i >> 11, rem = i & 2047;
    int j = rem >> 2, g = rem & 3;
    Wt4b[((size_t)(512 + kh) * 512 + j) * 4 + g] = W_hh[(size_t)(g * 512 + j) * 512 + kh];
  } else if (bid < 7297){
    int i = (bid - 6273) * 256 + tid;          // 512*512
    int k = i >> 9, n = i & 511;
    Wqt[i] = Wq[n * 512 + k];
  } else if (bid < 7305){
    int i = (bid - 7297) * 256 + tid;          // 2048
    int j = i >> 2, g = i & 3;
    bias4[i] = b_ih[g * 512 + j] + b_hh[g * 512 + j];
  } else if (bid < 7433){
    // xW0[b][j*4+g] = sum_p dec[b][p] * W_ih[g*512+j][p]  (t=0 x-contribution)
    __shared__ float dv[64];
    int b = bid - 7305;
    if (tid < 64) dv[tid] = dec[b * 64 + tid];
    __syncthreads();
    #pragma unroll
    for (int q = 0; q < 8; q++){
      int o = tid * 8 + q;                     // 0..2047
      int j = o >> 2, g = o & 3;
      const float* wr = W_ih + (size_t)(g * 512 + j) * 64;
      float acc = 0.f;
      #pragma unroll
      for (int p = 0; p < 64; p += 4)
        acc += dv[p] * wr[p] + dv[p+1] * wr[p+1] + dv[p+2] * wr[p+2] + dv[p+3] * wr[p+3];
      xW0[(size_t)b * 2048 + o] = acc;
    }
  } else {
    int i = (bid - 7433) * 256 + tid;          // 65536 + 65536
    if (i < 65536) cbuf[i] = c0[i];
    else hb0[i - 65536] = h0[i - 65536];
  }
}

// prep2 (needs Mt, bcomb from k_prep)
__global__ __launch_bounds__(256) void k_prep2(const float* __restrict__ Mt, const float* __restrict__ W_ih,
                                               const float* __restrict__ bcomb, float* __restrict__ Wt4b,
                                               float* __restrict__ biasx){
  const int bid = blockIdx.x, tid = threadIdx.x;
  if (bid < 4096){
    int i = bid * 256 + tid;                   // 512*2048
    int k = i >> 11, gcol = i & 2047;
    const float4* mr = (const float4*)(Mt + (size_t)k * 64);
    const float4* wr = (const float4*)(W_ih + (size_t)gcol * 64);
    float acc = 0.f;
    #pragma unroll
    for (int p = 0; p < 16; p++){
      float4 m = mr[p], w = wr[p];
      acc += m.x * w.x + m.y * w.y + m.z * w.z + m.w * w.w;
    }
    int g = gcol >> 9, j = gcol & 511;
    Wt4b[((size_t)k * 512 + j) * 4 + g] = acc;
  } else {
    #pragma unroll
    for (int q = 0; q < 8; q++){
      int o = tid * 8 + q;
      int j = o >> 2, g = o & 3;
      const float4* br = (const float4*)bcomb;
      const float4* wr = (const float4*)(W_ih + (size_t)(g * 512 + j) * 64);
      float acc = 0.f;
      #pragma unroll
      for (int p = 0; p < 16; p++){
        float4 b4 = br[p], w = wr[p];
        acc += b4.x * w.x + b4.y * w.y + b4.z * w.z + b4.w * w.w;
      }
      biasx[o] = acc;
    }
  }
}

// ---------------- K/V projection (bf16 MFMA GEMM, XCD-banded) ----------------
__global__ __launch_bounds__(256) void k_gemm_kv(const u16* __restrict__ Xb, const u16* __restrict__ Wkv,
                                                 const float* __restrict__ bk, const float* __restrict__ bv,
                                                 u16* __restrict__ Kb, u16* __restrict__ Vb){
  __shared__ __align__(16) u16 As[128 * 64];
  __shared__ __align__(16) u16 Bs[128 * 64];
  const int tid = threadIdx.x;
  const int lane = tid & 63, wid = tid >> 6;
  const int wm = wid >> 1, wn = wid & 1;
  const int mt = blockIdx.x * 64 + (blockIdx.y >> 3);
  const int nt = blockIdx.y & 7;
  const int n0 = nt * 128, m0 = mt * 128;

  f32x4 zero = {0.f, 0.f, 0.f, 0.f};
  f32x4 acc[4][4];
  #pragma unroll
  for (int i = 0; i < 4; i++)
    #pragma unroll
    for (int j = 0; j < 4; j++) acc[i][j] = zero;

  for (int kt = 0; kt < 512; kt += 64){
    #pragma unroll
    for (int s = 0; s < 4; s++){
      int slot = tid + 256 * s;                // 0..1023
      int r = slot >> 3, cg = slot & 7;
      int sw = (cg ^ (r & 7)) << 3;
      *(uint4*)&As[r * 64 + sw] = *(const uint4*)&Xb[(size_t)(m0 + r) * 512 + kt + cg * 8];
      *(uint4*)&Bs[r * 64 + sw] = *(const uint4*)&Wkv[(size_t)(n0 + r) * 512 + kt + cg * 8];
    }
    __syncthreads();
    #pragma unroll
    for (int ks = 0; ks < 2; ks++){
      bf16x8 af[4], bfr[4];
      int g = ks * 4 + (lane >> 4);
      int ra = wm * 64 + (lane & 15);
      int rb = wn * 64 + (lane & 15);
      #pragma unroll
      for (int i = 0; i < 4; i++){
        int r = ra + i * 16;
        af[i] = *(const bf16x8*)&As[r * 64 + ((g ^ (r & 7)) << 3)];
      }
      #pragma unroll
      for (int j = 0; j < 4; j++){
        int r = rb + j * 16;
        bfr[j] = *(const bf16x8*)&Bs[r * 64 + ((g ^ (r & 7)) << 3)];
      }
      #pragma unroll
      for (int i = 0; i < 4; i++)
        #pragma unroll
        for (int j = 0; j < 4; j++)
          acc[i][j] = __builtin_amdgcn_mfma_f32_16x16x32_bf16(af[i], bfr[j], acc[i][j], 0, 0, 0);
    }
    __syncthreads();
  }

  #pragma unroll
  for (int j = 0; j < 4; j++){
    int n = n0 + wn * 64 + j * 16 + (lane & 15);
    float bias = (n < 512) ? bk[n] : bv[n - 512];
    u16* dst = (n < 512) ? Kb : Vb;
    int nh = (n >> 6) & 7, hd = n & 63;
    #pragma unroll
    for (int i = 0; i < 4; i++){
      #pragma unroll
      for (int r = 0; r < 4; r++){
        int m = m0 + wm * 64 + i * 16 + (lane >> 4) * 4 + r;
        int b = m >> 9, l = m & 511;
        float val = acc[i][j][r] + bias;
        dst[((size_t)((b * 8 + nh) * 512 + l)) * 64 + hd] = f2bf(val);
      }
    }
  }
}

// ---------------- per-step kernels ----------------

// gates GEMM 128 x 2048 x K=1024 over z=[ctx_{t-1}, h_{t-1}] + LSTM + partial q.
__global__ __launch_bounds__(512) void k_gates3(const float* __restrict__ ctxprev, const float* __restrict__ hprev,
                                                float* __restrict__ hnext, float* __restrict__ cbuf,
                                                const float4* __restrict__ Wt4b, const float4* __restrict__ bias4,
                                                const float4* __restrict__ biasx, const float4* __restrict__ xW0,
                                                const float* __restrict__ Wqt, float* __restrict__ qp,
                                                int t0){
  __shared__ __align__(16) float zs[8 * 1024 + 256];   // 32 KB z/psum + 1 KB h-stage
  const int tid = threadIdx.x;
  const int jl = tid & 31, ks = tid >> 5;
  // XCD swizzle: same-jt blocks (sharing the W slice) colocate per XCD.
  const int bid = blockIdx.x;                          // 256 blocks
  const int xcd = bid & 7, idx = bid >> 3;
  const int jt = xcd * 2 + (idx & 1);
  const int bt = idx >> 1;
  const int b0 = bt * 8;
  const int j = jt * 32 + jl;

  // stage z = [ctx(512), h(512)] for 8 b-rows
  for (int i = tid; i < 8 * 256; i += 512){
    int r = i >> 8, c = (i & 255) << 2;
    float4 v;
    if (c < 512){
      if (!t0) v = *(const float4*)&ctxprev[(size_t)(b0 + r) * 512 + c];
      else     v = make_float4(0.f, 0.f, 0.f, 0.f);
    } else {
      v = *(const float4*)&hprev[(size_t)(b0 + r) * 512 + (c - 512)];
    }
    *(float4*)&zs[r * 1024 + c] = v;
  }
  __syncthreads();

  float4 acc[8];
  #pragma unroll
  for (int r = 0; r < 8; r++) acc[r] = make_float4(0.f, 0.f, 0.f, 0.f);

  const int k0 = ks * 64;
  const float4* Wp = Wt4b + (size_t)k0 * 512 + j;
  #pragma unroll 2
  for (int kk = 0; kk < 64; kk += 4){
    float4 w0 = Wp[(size_t)(kk + 0) * 512];
    float4 w1 = Wp[(size_t)(kk + 1) * 512];
    float4 w2 = Wp[(size_t)(kk + 2) * 512];
    float4 w3 = Wp[(size_t)(kk + 3) * 512];
    #pragma unroll
    for (int r = 0; r < 8; r++){
      const float4 xv = *(const float4*)&zs[r * 1024 + k0 + kk];
      acc[r].x += xv.x * w0.x; acc[r].y += xv.x * w0.y; acc[r].z += xv.x * w0.z; acc[r].w += xv.x * w0.w;
      acc[r].x += xv.y * w1.x; acc[r].y += xv.y * w1.y; acc[r].z += xv.y * w1.z; acc[r].w += xv.y * w1.w;
      acc[r].x += xv.z * w2.x; acc[r].y += xv.z * w2.y; acc[r].z += xv.z * w2.z; acc[r].w += xv.z * w2.w;
      acc[r].x += xv.w * w3.x; acc[r].y += xv.w * w3.y; acc[r].z += xv.w * w3.z; acc[r].w += xv.w * w3.w;
    }
  }

  // combine ks pairs within the wave, then 8 wave-partials via LDS
  #pragma unroll
  for (int r = 0; r < 8; r++){
    acc[r].x += __shfl_xor(acc[r].x, 32);
    acc[r].y += __shfl_xor(acc[r].y, 32);
    acc[r].z += __shfl_xor(acc[r].z, 32);
    acc[r].w += __shfl_xor(acc[r].w, 32);
  }
  __syncthreads();                                     // zs reads done; reuse as psum
  float4* ps = (float4*)zs;
  const int lane = tid & 63, wid = tid >> 6;
  if (lane < 32){
    #pragma unroll
    for (int r = 0; r < 8; r++) ps[(wid * 8 + r) * 32 + lane] = acc[r];
  }
  __syncthreads();

  if (tid < 256){
    const int r = tid >> 5, jj = tid & 31;
    const int j2 = jt * 32 + jj;
    float4 a = ps[r * 32 + jj];
    #pragma unroll
    for (int w = 1; w < 8; w++){
      float4 p = ps[(w * 8 + r) * 32 + jj];
      a.x += p.x; a.y += p.y; a.z += p.z; a.w += p.w;
    }
    const int b = b0 + r;
    float4 bb = bias4[j2];
    float4 bx = t0 ? xW0[(size_t)b * 512 + j2] : biasx[j2];
    float ai = a.x + bb.x + bx.x;
    float af = a.y + bb.y + bx.y;
    float ag = a.z + bb.z + bx.z;
    float ao = a.w + bb.w + bx.w;
    float c_old = cbuf[b * 512 + j2];
    float ig = 1.f / (1.f + __expf(-ai));
    float fg = 1.f / (1.f + __expf(-af));
    float e2 = __expf(2.f * ag);
    float gg = 1.f - 2.f / (e2 + 1.f);
    float og = 1.f / (1.f + __expf(-ao));
    float cn = fg * c_old + ig * gg;
    float ec = __expf(2.f * cn);
    float th = 1.f - 2.f / (ec + 1.f);
    cbuf[b * 512 + j2] = cn;
    float hv = og * th;
    hnext[b * 512 + j2] = hv;
    zs[8192 + tid] = hv;                               // h-stage (disjoint from psum)
  }
  __syncthreads();

  // partial q: qp[jt][b0+r][col] = sum_{j<32} h[r][j] * Wqt[jt*32+j][col]
  // threads (rg in 4) x (cgf in 128): each covers rows {rg, rg+4}, one float4
  // of columns -> Wqt read redundancy 4x (was 8x).
  {
    const int rg = tid >> 7, cgf = tid & 127;
    float4 f0 = make_float4(0.f, 0.f, 0.f, 0.f);
    float4 f1 = make_float4(0.f, 0.f, 0.f, 0.f);
    const float* wq = Wqt + (size_t)(jt * 32) * 512 + cgf * 4;
    const float* hv0 = &zs[8192 + rg * 32];
    const float* hv1 = &zs[8192 + (rg + 4) * 32];
    #pragma unroll 8
    for (int jj = 0; jj < 32; jj++){
      float4 w = *(const float4*)(wq + (size_t)jj * 512);
      float ha = hv0[jj], hb = hv1[jj];
      f0.x += ha * w.x; f0.y += ha * w.y; f0.z += ha * w.z; f0.w += ha * w.w;
      f1.x += hb * w.x; f1.y += hb * w.y; f1.z += hb * w.z; f1.w += hb * w.w;
    }
    float* q0 = qp + ((size_t)jt * 128 + b0 + rg) * 512 + cgf * 4;
    float* q1 = qp + ((size_t)jt * 128 + b0 + rg + 4) * 512 + cgf * 4;
    *(float4*)q0 = f0;
    *(float4*)q1 = f1;
  }
}

// attention: one block per (b,nh). K loads issued before the qp reduction
// (latency overlap); V prefetched into registers during softmax (T14-style
// async-STAGE); V consumed as uint4 (8 bf16/load).
__global__ __launch_bounds__(256) void k_attn2(const float* __restrict__ qp, const float* __restrict__ bq,
                                               const u16* __restrict__ Kb, const u16* __restrict__ Vb,
                                               float* __restrict__ attn_out, float* __restrict__ ctx_t, int t){
  const int bx = blockIdx.x;
  const int b = bx >> 3, nh = bx & 7;
  const int tid = threadIdx.x;
  const int lane = tid & 63, wid = tid >> 6;
  __shared__ float qs[64];
  __shared__ float sc[512];
  __shared__ float red[16];
  __shared__ __align__(16) float ctxp[4][64];

  // issue all K loads up front — independent of q, latency hides under qp sum
  const u16* Kp = Kb + (size_t)bx * (512 * 64);
  uint4 kr0[8], kr1[8];
  #pragma unroll
  for (int g = 0; g < 8; g++){
    kr0[g] = *(const uint4*)(Kp + (size_t)tid * 64 + g * 8);
    kr1[g] = *(const uint4*)(Kp + (size_t)(tid + 256) * 64 + g * 8);
  }

  if (tid < 64){
    float sum = bq[nh * 64 + tid];
    #pragma unroll
    for (int s = 0; s < 16; s++)
      sum += qp[((size_t)s * 128 + b) * 512 + nh * 64 + tid];
    qs[tid] = sum * 0.125f;                            // fold 1/sqrt(HD)
  }
  __syncthreads();

  float s0 = 0.f, s1 = 0.f;
  #pragma unroll
  for (int g = 0; g < 8; g++){
    const float* q8 = qs + g * 8;
    uint4 v = kr0[g];
    s0 += bfbits2f(v.x << 16)          * q8[0];
    s0 += bfbits2f(v.x & 0xffff0000u)  * q8[1];
    s0 += bfbits2f(v.y << 16)          * q8[2];
    s0 += bfbits2f(v.y & 0xffff0000u)  * q8[3];
    s0 += bfbits2f(v.z << 16)          * q8[4];
    s0 += bfbits2f(v.z & 0xffff0000u)  * q8[5];
    s0 += bfbits2f(v.w << 16)          * q8[6];
    s0 += bfbits2f(v.w & 0xffff0000u)  * q8[7];
    uint4 w = kr1[g];
    s1 += bfbits2f(w.x << 16)          * q8[0];
    s1 += bfbits2f(w.x & 0xffff0000u)  * q8[1];
    s1 += bfbits2f(w.y << 16)          * q8[2];
    s1 += bfbits2f(w.y & 0xffff0000u)  * q8[3];
    s1 += bfbits2f(w.z << 16)          * q8[4];
    s1 += bfbits2f(w.z & 0xffff0000u)  * q8[5];
    s1 += bfbits2f(w.w << 16)          * q8[6];
    s1 += bfbits2f(w.w & 0xffff0000u)  * q8[7];
  }

  // prefetch V into registers: latency hides under softmax reductions.
  // lane = (lq 8-rows, dq 8 d-octs); 16 iters cover 128 l-rows per wave-part.
  const int part = wid;
  const int lq = lane >> 3, dq = lane & 7;
  const u16* vp = Vb + (size_t)bx * (512 * 64) + (size_t)(part * 128 + lq) * 64 + dq * 8;
  uint4 vr[16];
  #pragma unroll
  for (int i = 0; i < 16; i++)
    vr[i] = *(const uint4*)(vp + (size_t)i * 512);     // 8 rows * 64 u16 stride

  float m = fmaxf(s0, s1);
  for (int off = 32; off > 0; off >>= 1) m = fmaxf(m, __shfl_down(m, off));
  if (lane == 0) red[wid] = m;
  __syncthreads();
  if (tid == 0) red[8] = fmaxf(fmaxf(red[0], red[1]), fmaxf(red[2], red[3]));
  __syncthreads();
  float mx = red[8];
  float e0 = __expf(s0 - mx), e1 = __expf(s1 - mx);
  float psum = e0 + e1;
  for (int off = 32; off > 0; off >>= 1) psum += __shfl_down(psum, off);
  if (lane == 0) red[4 + wid] = psum;
  __syncthreads();
  if (tid == 0) red[9] = 1.f / (red[4] + red[5] + red[6] + red[7]);
  __syncthreads();
  float inv = red[9];
  float a0 = e0 * inv, a1 = e1 * inv;
  sc[tid] = a0; sc[tid + 256] = a1;
  float* aout = attn_out + ((size_t)bx * HOR_ + t) * 512;
  aout[tid] = a0; aout[tid + 256] = a1;
  __syncthreads();

  // ctx from prefetched V
  float a[8];
  #pragma unroll
  for (int k = 0; k < 8; k++) a[k] = 0.f;
  #pragma unroll
  for (int i = 0; i < 16; i++){
    int l = part * 128 + i * 8 + lq;
    float w = sc[l];
    uint4 v = vr[i];
    a[0] += w * bfbits2f(v.x << 16);
    a[1] += w * bfbits2f(v.x & 0xffff0000u);
    a[2] += w * bfbits2f(v.y << 16);
    a[3] += w * bfbits2f(v.y & 0xffff0000u);
    a[4] += w * bfbits2f(v.z << 16);
    a[5] += w * bfbits2f(v.z & 0xffff0000u);
    a[6] += w * bfbits2f(v.w << 16);
    a[7] += w * bfbits2f(v.w & 0xffff0000u);
  }
  #pragma unroll
  for (int k = 0; k < 8; k++){
    a[k] += __shfl_xor(a[k], 8);
    a[k] += __shfl_xor(a[k], 16);
    a[k] += __shfl_xor(a[k], 32);
  }
  if (lq == 0){
    float4 c0v = make_float4(a[0], a[1], a[2], a[3]);
    float4 c1v = make_float4(a[4], a[5], a[6], a[7]);
    *(float4*)&ctxp[part][dq * 8] = c0v;
    *(float4*)&ctxp[part][dq * 8 + 4] = c1v;
  }
  __syncthreads();
  if (tid < 64)
    ctx_t[(size_t)b * 512 + nh * 64 + tid] = ctxp[0][tid] + ctxp[1][tid] + ctxp[2][tid] + ctxp[3][tid];
}

// batched pred (off critical path): pred[b][t] = ctx_all[t][b] @ Mt + bcomb
__global__ __launch_bounds__(256) void k_pred(const float* __restrict__ ctx_all, const float* __restrict__ Mt,
                                              const float* __restrict__ bcomb, float* __restrict__ outp){
  __shared__ float cs[512];
  __shared__ float pr[4][64];
  const int tid = threadIdx.x;
  const int b = blockIdx.x, t = blockIdx.y;
  const float* cx = ctx_all + ((size_t)t * B_ + b) * 512;
  cs[tid] = cx[tid];
  cs[tid + 256] = cx[tid + 256];
  __syncthreads();
  const int p = tid & 63, part = tid >> 6;
  float acc = 0.f;
  const float* mp = Mt + (size_t)(part * 128) * 64 + p;
  const float* cp = &cs[part * 128];
  #pragma unroll 8
  for (int i = 0; i < 128; i++)
    acc += cp[i] * mp[(size_t)i * 64];
  pr[part][p] = acc;
  __syncthreads();
  if (tid < 64){
    float v = pr[0][tid] + pr[1][tid] + pr[2][tid] + pr[3][tid] + bcomb[tid];
    outp[(size_t)b * (HOR_ * OUT_) + t * OUT_ + tid] = v;
  }
}

// ---------------- host launcher ----------------

extern "C" void kernel_launch(void* const* d_in, const int* in_sizes, int n_in,
                              void* d_out, int out_size, void* d_ws, size_t ws_size,
                              hipStream_t stream){
  const float* enc  = (const float*)d_in[0];
  const float* h0   = (const float*)d_in[1];
  const float* c0   = (const float*)d_in[2];
  const float* dec  = (const float*)d_in[3];
  const float* W_ih = (const float*)d_in[4];
  const float* W_hh = (const float*)d_in[5];
  const float* b_ih = (const float*)d_in[6];
  const float* b_hh = (const float*)d_in[7];
  const float* Wq   = (const float*)d_in[8];
  const float* bq   = (const float*)d_in[9];
  const float* Wk   = (const float*)d_in[10];
  const float* bk   = (const float*)d_in[11];
  const float* Wv   = (const float*)d_in[12];
  const float* bv   = (const float*)d_in[13];
  const float* Wo   = (const float*)d_in[14];
  const float* bo   = (const float*)d_in[15];
  const float* Wfc  = (const float*)d_in[16];
  const float* bfc  = (const float*)d_in[17];
  float* out = (float*)d_out;

  char* ws = (char*)d_ws;
  size_t off = 0;
  auto alloc = [&](size_t bytes){ void* p = ws + off; off += (bytes + 255) & ~(size_t)255; return p; };
  u16*   Xb    = (u16*)  alloc((size_t)B_ * L_ * H_ * 2);
  u16*   Kb    = (u16*)  alloc((size_t)B_ * NH_ * L_ * HD_ * 2);
  u16*   Vb    = (u16*)  alloc((size_t)B_ * NH_ * L_ * HD_ * 2);
  u16*   Wkv   = (u16*)  alloc((size_t)1024 * 512 * 2);
  float* Wt4b  = (float*)alloc((size_t)1024 * 512 * 4 * 4);   // [k][j][4 gates]
  float* Wqt   = (float*)alloc((size_t)512 * 512 * 4);
  float* Mt    = (float*)alloc((size_t)512 * 64 * 4);
  float* bcomb = (float*)alloc(64 * 4);
  float* bias4 = (float*)alloc((size_t)2048 * 4);
  float* biasx = (float*)alloc((size_t)2048 * 4);
  float* xW0   = (float*)alloc((size_t)B_ * 2048 * 4);
  float* hb0   = (float*)alloc((size_t)B_ * H_ * 4);
  float* hb1   = (float*)alloc((size_t)B_ * H_ * 4);
  float* cbuf  = (float*)alloc((size_t)B_ * H_ * 4);
  float* qp    = (float*)alloc((size_t)16 * B_ * 512 * 4);    // 16 jt-partials of q
  float* ctx_all = (float*)Xb;                // aliases Xb (dead after k_gemm_kv)
  if (off > ws_size){
    fprintf(stderr, "WORKSPACE TOO SMALL: need %zu, have %zu\n", off, ws_size);
  }

  float* out_pred = out;                                 // (B, HOR, OUT)
  float* out_attn = out + (size_t)B_ * HOR_ * OUT_;      // (B, NH, HOR, L)

  k_convert_x<<<4096, 256, 0, stream>>>((const float4*)enc, (ushort4*)Xb, (B_ * L_ * H_) / 4);
  k_prep<<<7945, 256, 0, stream>>>(Wk, Wv, W_ih, W_hh, b_ih, b_hh, Wq, Wfc, Wo, bo, bfc,
                                   dec, h0, c0, Wkv, Wt4b, Wqt, bias4, Mt, bcomb, xW0, hb0, cbuf);
  k_gemm_kv<<<dim3(8, 512), 256, 0, stream>>>(Xb, Wkv, bk, bv, Kb, Vb);
  k_prep2<<<4097, 256, 0, stream>>>(Mt, W_ih, bcomb, Wt4b, biasx);

  float* hb[2] = {hb0, hb1};
  for (int t = 0; t < HOR_; t++){
    const float* cprev = (t == 0) ? nullptr : (ctx_all + (size_t)(t - 1) * B_ * H_);
    k_gates3<<<256, 512, 0, stream>>>(cprev, hb[t & 1], hb[(t + 1) & 1], cbuf,
                                      (const float4*)Wt4b, (const float4*)bias4,
                                      (const float4*)biasx, (const float4*)xW0,
                                      Wqt, qp, t == 0 ? 1 : 0);
    k_attn2<<<1024, 256, 0, stream>>>(qp, bq, Kb, Vb, out_attn,
                                      ctx_all + (size_t)t * B_ * H_, t);
  }
  k_pred<<<dim3(128, 24), 256, 0, stream>>>(ctx_all, Mt, bcomb, out_pred);
}

// Round 7
// 1429.541 us; speedup vs baseline: 1.5184x; 1.0324x over previous
//
#include <hip/hip_runtime.h>
#include <cstdio>
#include <cstdint>

#define B_   128
#define L_   512
#define H_   512
#define IN_  64
#define OUT_ 64
#define NH_  8
#define HD_  64
#define HOR_ 24

typedef unsigned short u16;
typedef __attribute__((ext_vector_type(8))) __bf16 bf16x8;
typedef __attribute__((ext_vector_type(4))) float f32x4;

__device__ __forceinline__ float bfbits2f(uint32_t hi){ union { uint32_t u; float f; } v; v.u = hi; return v.f; }
__device__ __forceinline__ u16 f2bf(float f){
  union { uint32_t u; float f2; } v; v.f2 = f;
  uint32_t x = v.u;
  return (u16)((x + 0x7FFFu + ((x >> 16) & 1u)) >> 16);  // RNE
}

// ---------------- one-time prep ----------------

__global__ __launch_bounds__(256) void k_convert_x(const float4* __restrict__ X, ushort4* __restrict__ Xb, int n4){
  int i = blockIdx.x * blockDim.x + threadIdx.x;
  int stride = gridDim.x * blockDim.x;
  for (; i < n4; i += stride){
    float4 v = X[i];
    ushort4 o;
    o.x = f2bf(v.x); o.y = f2bf(v.y); o.z = f2bf(v.z); o.w = f2bf(v.w);
    Xb[i] = o;
  }
}

// fused small prep: block ranges (see comments inline)
__global__ __launch_bounds__(256) void k_prep(const float* __restrict__ Wk, const float* __restrict__ Wv,
                                              const float* __restrict__ W_ih, const float* __restrict__ W_hh,
                                              const float* __restrict__ b_ih, const float* __restrict__ b_hh,
                                              const float* __restrict__ Wq, const float* __restrict__ Wfc,
                                              const float* __restrict__ Wo, const float* __restrict__ bo,
                                              const float* __restrict__ bfc, const float* __restrict__ dec,
                                              const float* __restrict__ h0, const float* __restrict__ c0,
                                              u16* __restrict__ Wkv, float* __restrict__ Wt4b,
                                              float* __restrict__ Wqt, float* __restrict__ bias4,
                                              float* __restrict__ Mt, float* __restrict__ bcomb,
                                              float* __restrict__ xW0, float* __restrict__ hb0,
                                              float* __restrict__ cbuf){
  const int bid = blockIdx.x, tid = threadIdx.x;
  if (bid < 129){
    int i = bid * 256 + tid;
    if (i < 32768){
      int p = i >> 9, d = i & 511;
      float acc = 0.f;
      #pragma unroll 4
      for (int j = 0; j < 512; j++) acc += Wfc[p * 512 + j] * Wo[j * 512 + d];
      Mt[d * 64 + p] = acc;
    } else if (i < 32832){
      int p = i - 32768;
      float acc = bfc[p];
      for (int j = 0; j < 512; j++) acc += Wfc[p * 512 + j] * bo[j];
      bcomb[p] = acc;
    }
  } else if (bid < 2177){
    int i = (bid - 129) * 256 + tid;           // 1024*512
    int n = i >> 9;
    Wkv[i] = f2bf(n < 512 ? Wk[i] : Wv[i - 262144]);
  } else if (bid < 6273){
    int i = (bid - 2177) * 256 + tid;          // 512*512*4 -> W_hh into rows [512,1024)
    int kh = i >> 11, rem = i & 2047;
    int j = rem >> 2, g = rem & 3;
    Wt4b[((size_t)(512 + kh) * 512 + j) * 4 + g] = W_hh[(size_t)(g * 512 + j) * 512 + kh];
  } else if (bid < 7297){
    int i = (bid - 6273) * 256 + tid;          // 512*512
    int k = i >> 9, n = i & 511;
    Wqt[i] = Wq[n * 512 + k];
  } else if (bid < 7305){
    int i = (bid - 7297) * 256 + tid;          // 2048
    int j = i >> 2, g = i & 3;
    bias4[i] = b_ih[g * 512 + j] + b_hh[g * 512 + j];
  } else if (bid < 7433){
    // xW0[b][j*4+g] = sum_p dec[b][p] * W_ih[g*512+j][p]  (t=0 x-contribution)
    __shared__ float dv[64];
    int b = bid - 7305;
    if (tid < 64) dv[tid] = dec[b * 64 + tid];
    __syncthreads();
    #pragma unroll
    for (int q = 0; q < 8; q++){
      int o = tid * 8 + q;                     // 0..2047
      int j = o >> 2, g = o & 3;
      const float* wr = W_ih + (size_t)(g * 512 + j) * 64;
      float acc = 0.f;
      #pragma unroll
      for (int p = 0; p < 64; p += 4)
        acc += dv[p] * wr[p] + dv[p+1] * wr[p+1] + dv[p+2] * wr[p+2] + dv[p+3] * wr[p+3];
      xW0[(size_t)b * 2048 + o] = acc;
    }
  } else {
    int i = (bid - 7433) * 256 + tid;          // 65536 + 65536
    if (i < 65536) cbuf[i] = c0[i];
    else hb0[i - 65536] = h0[i - 65536];
  }
}

// prep2 (needs Mt, bcomb from k_prep)
__global__ __launch_bounds__(256) void k_prep2(const float* __restrict__ Mt, const float* __restrict__ W_ih,
                                               const float* __restrict__ bcomb, float* __restrict__ Wt4b,
                                               float* __restrict__ biasx){
  const int bid = blockIdx.x, tid = threadIdx.x;
  if (bid < 4096){
    int i = bid * 256 + tid;                   // 512*2048
    int k = i >> 11, gcol = i & 2047;
    const float4* mr = (const float4*)(Mt + (size_t)k * 64);
    const float4* wr = (const float4*)(W_ih + (size_t)gcol * 64);
    float acc = 0.f;
    #pragma unroll
    for (int p = 0; p < 16; p++){
      float4 m = mr[p], w = wr[p];
      acc += m.x * w.x + m.y * w.y + m.z * w.z + m.w * w.w;
    }
    int g = gcol >> 9, j = gcol & 511;
    Wt4b[((size_t)k * 512 + j) * 4 + g] = acc;
  } else {
    #pragma unroll
    for (int q = 0; q < 8; q++){
      int o = tid * 8 + q;
      int j = o >> 2, g = o & 3;
      const float4* br = (const float4*)bcomb;
      const float4* wr = (const float4*)(W_ih + (size_t)(g * 512 + j) * 64);
      float acc = 0.f;
      #pragma unroll
      for (int p = 0; p < 16; p++){
        float4 b4 = br[p], w = wr[p];
        acc += b4.x * w.x + b4.y * w.y + b4.z * w.z + b4.w * w.w;
      }
      biasx[o] = acc;
    }
  }
}

// ---------------- K/V projection (bf16 MFMA GEMM, XCD-banded) ----------------
__global__ __launch_bounds__(256) void k_gemm_kv(const u16* __restrict__ Xb, const u16* __restrict__ Wkv,
                                                 const float* __restrict__ bk, const float* __restrict__ bv,
                                                 u16* __restrict__ Kb, u16* __restrict__ Vb){
  __shared__ __align__(16) u16 As[128 * 64];
  __shared__ __align__(16) u16 Bs[128 * 64];
  const int tid = threadIdx.x;
  const int lane = tid & 63, wid = tid >> 6;
  const int wm = wid >> 1, wn = wid & 1;
  const int mt = blockIdx.x * 64 + (blockIdx.y >> 3);
  const int nt = blockIdx.y & 7;
  const int n0 = nt * 128, m0 = mt * 128;

  f32x4 zero = {0.f, 0.f, 0.f, 0.f};
  f32x4 acc[4][4];
  #pragma unroll
  for (int i = 0; i < 4; i++)
    #pragma unroll
    for (int j = 0; j < 4; j++) acc[i][j] = zero;

  for (int kt = 0; kt < 512; kt += 64){
    #pragma unroll
    for (int s = 0; s < 4; s++){
      int slot = tid + 256 * s;                // 0..1023
      int r = slot >> 3, cg = slot & 7;
      int sw = (cg ^ (r & 7)) << 3;
      *(uint4*)&As[r * 64 + sw] = *(const uint4*)&Xb[(size_t)(m0 + r) * 512 + kt + cg * 8];
      *(uint4*)&Bs[r * 64 + sw] = *(const uint4*)&Wkv[(size_t)(n0 + r) * 512 + kt + cg * 8];
    }
    __syncthreads();
    #pragma unroll
    for (int ks = 0; ks < 2; ks++){
      bf16x8 af[4], bfr[4];
      int g = ks * 4 + (lane >> 4);
      int ra = wm * 64 + (lane & 15);
      int rb = wn * 64 + (lane & 15);
      #pragma unroll
      for (int i = 0; i < 4; i++){
        int r = ra + i * 16;
        af[i] = *(const bf16x8*)&As[r * 64 + ((g ^ (r & 7)) << 3)];
      }
      #pragma unroll
      for (int j = 0; j < 4; j++){
        int r = rb + j * 16;
        bfr[j] = *(const bf16x8*)&Bs[r * 64 + ((g ^ (r & 7)) << 3)];
      }
      #pragma unroll
      for (int i = 0; i < 4; i++)
        #pragma unroll
        for (int j = 0; j < 4; j++)
          acc[i][j] = __builtin_amdgcn_mfma_f32_16x16x32_bf16(af[i], bfr[j], acc[i][j], 0, 0, 0);
    }
    __syncthreads();
  }

  #pragma unroll
  for (int j = 0; j < 4; j++){
    int n = n0 + wn * 64 + j * 16 + (lane & 15);
    float bias = (n < 512) ? bk[n] : bv[n - 512];
    u16* dst = (n < 512) ? Kb : Vb;
    int nh = (n >> 6) & 7, hd = n & 63;
    #pragma unroll
    for (int i = 0; i < 4; i++){
      #pragma unroll
      for (int r = 0; r < 4; r++){
        int m = m0 + wm * 64 + i * 16 + (lane >> 4) * 4 + r;
        int b = m >> 9, l = m & 511;
        float val = acc[i][j][r] + bias;
        dst[((size_t)((b * 8 + nh) * 512 + l)) * 64 + hd] = f2bf(val);
      }
    }
  }
}

// ---------------- per-step kernels ----------------

// gates GEMM 128 x 2048 x K=1024 over z=[ctx_{t-1}, h_{t-1}] + LSTM + partial q.
__global__ __launch_bounds__(512) void k_gates3(const float* __restrict__ ctxprev, const float* __restrict__ hprev,
                                                float* __restrict__ hnext, float* __restrict__ cbuf,
                                                const float4* __restrict__ Wt4b, const float4* __restrict__ bias4,
                                                const float4* __restrict__ biasx, const float4* __restrict__ xW0,
                                                const float* __restrict__ Wqt, float* __restrict__ qp,
                                                int t0){
  __shared__ __align__(16) float zs[8 * 1024 + 256];   // 32 KB z/psum + 1 KB h-stage
  const int tid = threadIdx.x;
  const int jl = tid & 31, ks = tid >> 5;
  // XCD swizzle: same-jt blocks (sharing the W slice) colocate per XCD.
  const int bid = blockIdx.x;                          // 256 blocks
  const int xcd = bid & 7, idx = bid >> 3;
  const int jt = xcd * 2 + (idx & 1);
  const int bt = idx >> 1;
  const int b0 = bt * 8;
  const int j = jt * 32 + jl;

  // stage z = [ctx(512), h(512)] for 8 b-rows
  for (int i = tid; i < 8 * 256; i += 512){
    int r = i >> 8, c = (i & 255) << 2;
    float4 v;
    if (c < 512){
      if (!t0) v = *(const float4*)&ctxprev[(size_t)(b0 + r) * 512 + c];
      else     v = make_float4(0.f, 0.f, 0.f, 0.f);
    } else {
      v = *(const float4*)&hprev[(size_t)(b0 + r) * 512 + (c - 512)];
    }
    *(float4*)&zs[r * 1024 + c] = v;
  }
  __syncthreads();

  float4 acc[8];
  #pragma unroll
  for (int r = 0; r < 8; r++) acc[r] = make_float4(0.f, 0.f, 0.f, 0.f);

  const int k0 = ks * 64;
  const float4* Wp = Wt4b + (size_t)k0 * 512 + j;
  #pragma unroll 2
  for (int kk = 0; kk < 64; kk += 4){
    float4 w0 = Wp[(size_t)(kk + 0) * 512];
    float4 w1 = Wp[(size_t)(kk + 1) * 512];
    float4 w2 = Wp[(size_t)(kk + 2) * 512];
    float4 w3 = Wp[(size_t)(kk + 3) * 512];
    #pragma unroll
    for (int r = 0; r < 8; r++){
      const float4 xv = *(const float4*)&zs[r * 1024 + k0 + kk];
      acc[r].x += xv.x * w0.x; acc[r].y += xv.x * w0.y; acc[r].z += xv.x * w0.z; acc[r].w += xv.x * w0.w;
      acc[r].x += xv.y * w1.x; acc[r].y += xv.y * w1.y; acc[r].z += xv.y * w1.z; acc[r].w += xv.y * w1.w;
      acc[r].x += xv.z * w2.x; acc[r].y += xv.z * w2.y; acc[r].z += xv.z * w2.z; acc[r].w += xv.z * w2.w;
      acc[r].x += xv.w * w3.x; acc[r].y += xv.w * w3.y; acc[r].z += xv.w * w3.z; acc[r].w += xv.w * w3.w;
    }
  }

  // combine ks pairs within the wave, then 8 wave-partials via LDS
  #pragma unroll
  for (int r = 0; r < 8; r++){
    acc[r].x += __shfl_xor(acc[r].x, 32);
    acc[r].y += __shfl_xor(acc[r].y, 32);
    acc[r].z += __shfl_xor(acc[r].z, 32);
    acc[r].w += __shfl_xor(acc[r].w, 32);
  }
  __syncthreads();                                     // zs reads done; reuse as psum
  float4* ps = (float4*)zs;
  const int lane = tid & 63, wid = tid >> 6;
  if (lane < 32){
    #pragma unroll
    for (int r = 0; r < 8; r++) ps[(wid * 8 + r) * 32 + lane] = acc[r];
  }
  __syncthreads();

  if (tid < 256){
    const int r = tid >> 5, jj = tid & 31;
    const int j2 = jt * 32 + jj;
    float4 a = ps[r * 32 + jj];
    #pragma unroll
    for (int w = 1; w < 8; w++){
      float4 p = ps[(w * 8 + r) * 32 + jj];
      a.x += p.x; a.y += p.y; a.z += p.z; a.w += p.w;
    }
    const int b = b0 + r;
    float4 bb = bias4[j2];
    float4 bx = t0 ? xW0[(size_t)b * 512 + j2] : biasx[j2];
    float ai = a.x + bb.x + bx.x;
    float af = a.y + bb.y + bx.y;
    float ag = a.z + bb.z + bx.z;
    float ao = a.w + bb.w + bx.w;
    float c_old = cbuf[b * 512 + j2];
    float ig = 1.f / (1.f + __expf(-ai));
    float fg = 1.f / (1.f + __expf(-af));
    float e2 = __expf(2.f * ag);
    float gg = 1.f - 2.f / (e2 + 1.f);
    float og = 1.f / (1.f + __expf(-ao));
    float cn = fg * c_old + ig * gg;
    float ec = __expf(2.f * cn);
    float th = 1.f - 2.f / (ec + 1.f);
    cbuf[b * 512 + j2] = cn;
    float hv = og * th;
    hnext[b * 512 + j2] = hv;
    zs[8192 + tid] = hv;                               // h-stage (disjoint from psum)
  }
  __syncthreads();

  // partial q: qp[jt][b0+r][col] = sum_{j<32} h[r][j] * Wqt[jt*32+j][col]
  // threads (rg in 4) x (cgf in 128): each covers rows {rg, rg+4}, one float4
  // of columns -> Wqt read redundancy 4x.
  {
    const int rg = tid >> 7, cgf = tid & 127;
    float4 f0 = make_float4(0.f, 0.f, 0.f, 0.f);
    float4 f1 = make_float4(0.f, 0.f, 0.f, 0.f);
    const float* wq = Wqt + (size_t)(jt * 32) * 512 + cgf * 4;
    const float* hv0 = &zs[8192 + rg * 32];
    const float* hv1 = &zs[8192 + (rg + 4) * 32];
    #pragma unroll 8
    for (int jj = 0; jj < 32; jj++){
      float4 w = *(const float4*)(wq + (size_t)jj * 512);
      float ha = hv0[jj], hb = hv1[jj];
      f0.x += ha * w.x; f0.y += ha * w.y; f0.z += ha * w.z; f0.w += ha * w.w;
      f1.x += hb * w.x; f1.y += hb * w.y; f1.z += hb * w.z; f1.w += hb * w.w;
    }
    float* q0 = qp + ((size_t)jt * 128 + b0 + rg) * 512 + cgf * 4;
    float* q1 = qp + ((size_t)jt * 128 + b0 + rg + 4) * 512 + cgf * 4;
    *(float4*)q0 = f0;
    *(float4*)q1 = f1;
  }
}

// attention v3: 512 threads per (b,nh) block. One K-row per thread (kr[8] =
// 32 VGPR), 8 V-loads per thread (vr[8] = 32 VGPR) -> ~half the VGPR of v2,
// 2x resident waves, 2x outstanding loads for the L3-resident K/V stream.
__global__ __launch_bounds__(512) void k_attn3(const float* __restrict__ qp, const float* __restrict__ bq,
                                               const u16* __restrict__ Kb, const u16* __restrict__ Vb,
                                               float* __restrict__ attn_out, float* __restrict__ ctx_t, int t){
  const int bx = blockIdx.x;
  const int b = bx >> 3, nh = bx & 7;
  const int tid = threadIdx.x;
  const int lane = tid & 63, wid = tid >> 6;     // 8 waves
  __shared__ float qs[64];
  __shared__ float sc[512];
  __shared__ float red[20];
  __shared__ __align__(16) float ctxp[8][64];

  // K prefetch: one row per thread; issues before qp-sum so latency hides.
  const u16* Kp = Kb + (size_t)bx * (512 * 64);
  uint4 kr[8];
  #pragma unroll
  for (int g = 0; g < 8; g++)
    kr[g] = *(const uint4*)(Kp + (size_t)tid * 64 + g * 8);

  if (tid < 64){
    float sum = bq[nh * 64 + tid];
    #pragma unroll
    for (int s = 0; s < 16; s++)
      sum += qp[((size_t)s * 128 + b) * 512 + nh * 64 + tid];
    qs[tid] = sum * 0.125f;                      // fold 1/sqrt(HD)
  }
  __syncthreads();

  float s0 = 0.f;
  #pragma unroll
  for (int g = 0; g < 8; g++){
    const float* q8 = qs + g * 8;
    uint4 v = kr[g];
    s0 += bfbits2f(v.x << 16)          * q8[0];
    s0 += bfbits2f(v.x & 0xffff0000u)  * q8[1];
    s0 += bfbits2f(v.y << 16)          * q8[2];
    s0 += bfbits2f(v.y & 0xffff0000u)  * q8[3];
    s0 += bfbits2f(v.z << 16)          * q8[4];
    s0 += bfbits2f(v.z & 0xffff0000u)  * q8[5];
    s0 += bfbits2f(v.w << 16)          * q8[6];
    s0 += bfbits2f(v.w & 0xffff0000u)  * q8[7];
  }

  // V prefetch during softmax: wave part covers 64 l-rows; lane=(lq 8-rows,
  // dq 8 d-octs); 8 uint4 per thread.
  const int part = wid;
  const int lq = lane >> 3, dq = lane & 7;
  const u16* vp = Vb + (size_t)bx * (512 * 64) + (size_t)(part * 64 + lq) * 64 + dq * 8;
  uint4 vr[8];
  #pragma unroll
  for (int i = 0; i < 8; i++)
    vr[i] = *(const uint4*)(vp + (size_t)i * 512);   // 8 rows * 64 u16 stride

  float m = s0;
  for (int off = 32; off > 0; off >>= 1) m = fmaxf(m, __shfl_down(m, off));
  if (lane == 0) red[wid] = m;
  __syncthreads();
  if (tid == 0){
    float mm = red[0];
    #pragma unroll
    for (int w = 1; w < 8; w++) mm = fmaxf(mm, red[w]);
    red[16] = mm;
  }
  __syncthreads();
  float mx = red[16];
  float e0 = __expf(s0 - mx);
  float psum = e0;
  for (int off = 32; off > 0; off >>= 1) psum += __shfl_down(psum, off);
  if (lane == 0) red[8 + wid] = psum;
  __syncthreads();
  if (tid == 0){
    float ss = red[8];
    #pragma unroll
    for (int w = 1; w < 8; w++) ss += red[8 + w];
    red[17] = 1.f / ss;
  }
  __syncthreads();
  float a0 = e0 * red[17];
  sc[tid] = a0;
  attn_out[((size_t)bx * HOR_ + t) * 512 + tid] = a0;
  __syncthreads();

  // ctx from prefetched V
  float a[8];
  #pragma unroll
  for (int k = 0; k < 8; k++) a[k] = 0.f;
  #pragma unroll
  for (int i = 0; i < 8; i++){
    int l = part * 64 + i * 8 + lq;
    float w = sc[l];
    uint4 v = vr[i];
    a[0] += w * bfbits2f(v.x << 16);
    a[1] += w * bfbits2f(v.x & 0xffff0000u);
    a[2] += w * bfbits2f(v.y << 16);
    a[3] += w * bfbits2f(v.y & 0xffff0000u);
    a[4] += w * bfbits2f(v.z << 16);
    a[5] += w * bfbits2f(v.z & 0xffff0000u);
    a[6] += w * bfbits2f(v.w << 16);
    a[7] += w * bfbits2f(v.w & 0xffff0000u);
  }
  #pragma unroll
  for (int k = 0; k < 8; k++){
    a[k] += __shfl_xor(a[k], 8);
    a[k] += __shfl_xor(a[k], 16);
    a[k] += __shfl_xor(a[k], 32);
  }
  if (lq == 0){
    float4 c0v = make_float4(a[0], a[1], a[2], a[3]);
    float4 c1v = make_float4(a[4], a[5], a[6], a[7]);
    *(float4*)&ctxp[part][dq * 8] = c0v;
    *(float4*)&ctxp[part][dq * 8 + 4] = c1v;
  }
  __syncthreads();
  if (tid < 64){
    float s = ctxp[0][tid];
    #pragma unroll
    for (int p = 1; p < 8; p++) s += ctxp[p][tid];
    ctx_t[(size_t)b * 512 + nh * 64 + tid] = s;
  }
}

// batched pred (off critical path): pred[b][t] = ctx_all[t][b] @ Mt + bcomb
__global__ __launch_bounds__(256) void k_pred(const float* __restrict__ ctx_all, const float* __restrict__ Mt,
                                              const float* __restrict__ bcomb, float* __restrict__ outp){
  __shared__ float cs[512];
  __shared__ float pr[4][64];
  const int tid = threadIdx.x;
  const int b = blockIdx.x, t = blockIdx.y;
  const float* cx = ctx_all + ((size_t)t * B_ + b) * 512;
  cs[tid] = cx[tid];
  cs[tid + 256] = cx[tid + 256];
  __syncthreads();
  const int p = tid & 63, part = tid >> 6;
  float acc = 0.f;
  const float* mp = Mt + (size_t)(part * 128) * 64 + p;
  const float* cp = &cs[part * 128];
  #pragma unroll 8
  for (int i = 0; i < 128; i++)
    acc += cp[i] * mp[(size_t)i * 64];
  pr[part][p] = acc;
  __syncthreads();
  if (tid < 64){
    float v = pr[0][tid] + pr[1][tid] + pr[2][tid] + pr[3][tid] + bcomb[tid];
    outp[(size_t)b * (HOR_ * OUT_) + t * OUT_ + tid] = v;
  }
}

// ---------------- host launcher ----------------

extern "C" void kernel_launch(void* const* d_in, const int* in_sizes, int n_in,
                              void* d_out, int out_size, void* d_ws, size_t ws_size,
                              hipStream_t stream){
  const float* enc  = (const float*)d_in[0];
  const float* h0   = (const float*)d_in[1];
  const float* c0   = (const float*)d_in[2];
  const float* dec  = (const float*)d_in[3];
  const float* W_ih = (const float*)d_in[4];
  const float* W_hh = (const float*)d_in[5];
  const float* b_ih = (const float*)d_in[6];
  const float* b_hh = (const float*)d_in[7];
  const float* Wq   = (const float*)d_in[8];
  const float* bq   = (const float*)d_in[9];
  const float* Wk   = (const float*)d_in[10];
  const float* bk   = (const float*)d_in[11];
  const float* Wv   = (const float*)d_in[12];
  const float* bv   = (const float*)d_in[13];
  const float* Wo   = (const float*)d_in[14];
  const float* bo   = (const float*)d_in[15];
  const float* Wfc  = (const float*)d_in[16];
  const float* bfc  = (const float*)d_in[17];
  float* out = (float*)d_out;

  char* ws = (char*)d_ws;
  size_t off = 0;
  auto alloc = [&](size_t bytes){ void* p = ws + off; off += (bytes + 255) & ~(size_t)255; return p; };
  u16*   Xb    = (u16*)  alloc((size_t)B_ * L_ * H_ * 2);
  u16*   Kb    = (u16*)  alloc((size_t)B_ * NH_ * L_ * HD_ * 2);
  u16*   Vb    = (u16*)  alloc((size_t)B_ * NH_ * L_ * HD_ * 2);
  u16*   Wkv   = (u16*)  alloc((size_t)1024 * 512 * 2);
  float* Wt4b  = (float*)alloc((size_t)1024 * 512 * 4 * 4);   // [k][j][4 gates]
  float* Wqt   = (float*)alloc((size_t)512 * 512 * 4);
  float* Mt    = (float*)alloc((size_t)512 * 64 * 4);
  float* bcomb = (float*)alloc(64 * 4);
  float* bias4 = (float*)alloc((size_t)2048 * 4);
  float* biasx = (float*)alloc((size_t)2048 * 4);
  float* xW0   = (float*)alloc((size_t)B_ * 2048 * 4);
  float* hb0   = (float*)alloc((size_t)B_ * H_ * 4);
  float* hb1   = (float*)alloc((size_t)B_ * H_ * 4);
  float* cbuf  = (float*)alloc((size_t)B_ * H_ * 4);
  float* qp    = (float*)alloc((size_t)16 * B_ * 512 * 4);    // 16 jt-partials of q
  float* ctx_all = (float*)Xb;                // aliases Xb (dead after k_gemm_kv)
  if (off > ws_size){
    fprintf(stderr, "WORKSPACE TOO SMALL: need %zu, have %zu\n", off, ws_size);
  }

  float* out_pred = out;                                 // (B, HOR, OUT)
  float* out_attn = out + (size_t)B_ * HOR_ * OUT_;      // (B, NH, HOR, L)

  k_convert_x<<<4096, 256, 0, stream>>>((const float4*)enc, (ushort4*)Xb, (B_ * L_ * H_) / 4);
  k_prep<<<7945, 256, 0, stream>>>(Wk, Wv, W_ih, W_hh, b_ih, b_hh, Wq, Wfc, Wo, bo, bfc,
                                   dec, h0, c0, Wkv, Wt4b, Wqt, bias4, Mt, bcomb, xW0, hb0, cbuf);
  k_gemm_kv<<<dim3(8, 512), 256, 0, stream>>>(Xb, Wkv, bk, bv, Kb, Vb);
  k_prep2<<<4097, 256, 0, stream>>>(Mt, W_ih, bcomb, Wt4b, biasx);

  float* hb[2] = {hb0, hb1};
  for (int t = 0; t < HOR_; t++){
    const float* cprev = (t == 0) ? nullptr : (ctx_all + (size_t)(t - 1) * B_ * H_);
    k_gates3<<<256, 512, 0, stream>>>(cprev, hb[t & 1], hb[(t + 1) & 1], cbuf,
                                      (const float4*)Wt4b, (const float4*)bias4,
                                      (const float4*)biasx, (const float4*)xW0,
                                      Wqt, qp, t == 0 ? 1 : 0);
    k_attn3<<<1024, 512, 0, stream>>>(qp, bq, Kb, Vb, out_attn,
                                      ctx_all + (size_t)t * B_ * H_, t);
  }
  k_pred<<<dim3(128, 24), 256, 0, stream>>>(ctx_all, Mt, bcomb, out_pred);
}

// Round 8
// 1415.131 us; speedup vs baseline: 1.5339x; 1.0102x over previous
//
#include <hip/hip_runtime.h>
#include <cstdio>
#include <cstdint>

#define B_   128
#define L_   512
#define H_   512
#define IN_  64
#define OUT_ 64
#define NH_  8
#define HD_  64
#define HOR_ 24

typedef unsigned short u16;
typedef __attribute__((ext_vector_type(8))) __bf16 bf16x8;
typedef __attribute__((ext_vector_type(4))) float f32x4;

__device__ __forceinline__ float bfbits2f(uint32_t hi){ union { uint32_t u; float f; } v; v.u = hi; return v.f; }
__device__ __forceinline__ u16 f2bf(float f){
  union { uint32_t u; float f2; } v; v.f2 = f;
  uint32_t x = v.u;
  return (u16)((x + 0x7FFFu + ((x >> 16) & 1u)) >> 16);  // RNE
}

// ---------------- one-time prep ----------------

__global__ __launch_bounds__(256) void k_convert_x(const float4* __restrict__ X, ushort4* __restrict__ Xb, int n4){
  int i = blockIdx.x * blockDim.x + threadIdx.x;
  int stride = gridDim.x * blockDim.x;
  for (; i < n4; i += stride){
    float4 v = X[i];
    ushort4 o;
    o.x = f2bf(v.x); o.y = f2bf(v.y); o.z = f2bf(v.z); o.w = f2bf(v.w);
    Xb[i] = o;
  }
}

// fused small prep: block ranges (see comments inline)
__global__ __launch_bounds__(256) void k_prep(const float* __restrict__ Wk, const float* __restrict__ Wv,
                                              const float* __restrict__ W_ih, const float* __restrict__ W_hh,
                                              const float* __restrict__ b_ih, const float* __restrict__ b_hh,
                                              const float* __restrict__ Wq, const float* __restrict__ Wfc,
                                              const float* __restrict__ Wo, const float* __restrict__ bo,
                                              const float* __restrict__ bfc, const float* __restrict__ dec,
                                              const float* __restrict__ h0, const float* __restrict__ c0,
                                              u16* __restrict__ Wkv, float* __restrict__ Wt4b,
                                              float* __restrict__ Wqt, float* __restrict__ bias4,
                                              float* __restrict__ Mt, float* __restrict__ bcomb,
                                              float* __restrict__ xW0, float* __restrict__ hb0,
                                              float* __restrict__ cbuf){
  const int bid = blockIdx.x, tid = threadIdx.x;
  if (bid < 129){
    int i = bid * 256 + tid;
    if (i < 32768){
      int p = i >> 9, d = i & 511;
      float acc = 0.f;
      #pragma unroll 4
      for (int j = 0; j < 512; j++) acc += Wfc[p * 512 + j] * Wo[j * 512 + d];
      Mt[d * 64 + p] = acc;
    } else if (i < 32832){
      int p = i - 32768;
      float acc = bfc[p];
      for (int j = 0; j < 512; j++) acc += Wfc[p * 512 + j] * bo[j];
      bcomb[p] = acc;
    }
  } else if (bid < 2177){
    int i = (bid - 129) * 256 + tid;           // 1024*512
    int n = i >> 9;
    Wkv[i] = f2bf(n < 512 ? Wk[i] : Wv[i - 262144]);
  } else if (bid < 6273){
    int i = (bid - 2177) * 256 + tid;          // 512*512*4 -> W_hh into rows [512,1024)
    int kh = i >> 11, rem = i & 2047;
    int j = rem >> 2, g = rem & 3;
    Wt4b[((size_t)(512 + kh) * 512 + j) * 4 + g] = W_hh[(size_t)(g * 512 + j) * 512 + kh];
  } else if (bid < 7297){
    int i = (bid - 6273) * 256 + tid;          // 512*512
    int k = i >> 9, n = i & 511;
    Wqt[i] = Wq[n * 512 + k];
  } else if (bid < 7305){
    int i = (bid - 7297) * 256 + tid;          // 2048
    int j = i >> 2, g = i & 3;
    bias4[i] = b_ih[g * 512 + j] + b_hh[g * 512 + j];
  } else if (bid < 7433){
    // xW0[b][j*4+g] = sum_p dec[b][p] * W_ih[g*512+j][p]  (t=0 x-contribution)
    __shared__ float dv[64];
    int b = bid - 7305;
    if (tid < 64) dv[tid] = dec[b * 64 + tid];
    __syncthreads();
    #pragma unroll
    for (int q = 0; q < 8; q++){
      int o = tid * 8 + q;                     // 0..2047
      int j = o >> 2, g = o & 3;
      const float* wr = W_ih + (size_t)(g * 512 + j) * 64;
      float acc = 0.f;
      #pragma unroll
      for (int p = 0; p < 64; p += 4)
        acc += dv[p] * wr[p] + dv[p+1] * wr[p+1] + dv[p+2] * wr[p+2] + dv[p+3] * wr[p+3];
      xW0[(size_t)b * 2048 + o] = acc;
    }
  } else {
    int i = (bid - 7433) * 256 + tid;          // 65536 + 65536
    if (i < 65536) cbuf[i] = c0[i];
    else hb0[i - 65536] = h0[i - 65536];
  }
}

// prep2 (needs Mt, bcomb from k_prep)
__global__ __launch_bounds__(256) void k_prep2(const float* __restrict__ Mt, const float* __restrict__ W_ih,
                                               const float* __restrict__ bcomb, float* __restrict__ Wt4b,
                                               float* __restrict__ biasx){
  const int bid = blockIdx.x, tid = threadIdx.x;
  if (bid < 4096){
    int i = bid * 256 + tid;                   // 512*2048
    int k = i >> 11, gcol = i & 2047;
    const float4* mr = (const float4*)(Mt + (size_t)k * 64);
    const float4* wr = (const float4*)(W_ih + (size_t)gcol * 64);
    float acc = 0.f;
    #pragma unroll
    for (int p = 0; p < 16; p++){
      float4 m = mr[p], w = wr[p];
      acc += m.x * w.x + m.y * w.y + m.z * w.z + m.w * w.w;
    }
    int g = gcol >> 9, j = gcol & 511;
    Wt4b[((size_t)k * 512 + j) * 4 + g] = acc;
  } else {
    #pragma unroll
    for (int q = 0; q < 8; q++){
      int o = tid * 8 + q;
      int j = o >> 2, g = o & 3;
      const float4* br = (const float4*)bcomb;
      const float4* wr = (const float4*)(W_ih + (size_t)(g * 512 + j) * 64);
      float acc = 0.f;
      #pragma unroll
      for (int p = 0; p < 16; p++){
        float4 b4 = br[p], w = wr[p];
        acc += b4.x * w.x + b4.y * w.y + b4.z * w.z + b4.w * w.w;
      }
      biasx[o] = acc;
    }
  }
}

// ---------------- K/V projection (bf16 MFMA GEMM, XCD-banded) ----------------
__global__ __launch_bounds__(256) void k_gemm_kv(const u16* __restrict__ Xb, const u16* __restrict__ Wkv,
                                                 const float* __restrict__ bk, const float* __restrict__ bv,
                                                 u16* __restrict__ Kb, u16* __restrict__ Vb){
  __shared__ __align__(16) u16 As[128 * 64];
  __shared__ __align__(16) u16 Bs[128 * 64];
  const int tid = threadIdx.x;
  const int lane = tid & 63, wid = tid >> 6;
  const int wm = wid >> 1, wn = wid & 1;
  const int mt = blockIdx.x * 64 + (blockIdx.y >> 3);
  const int nt = blockIdx.y & 7;
  const int n0 = nt * 128, m0 = mt * 128;

  f32x4 zero = {0.f, 0.f, 0.f, 0.f};
  f32x4 acc[4][4];
  #pragma unroll
  for (int i = 0; i < 4; i++)
    #pragma unroll
    for (int j = 0; j < 4; j++) acc[i][j] = zero;

  for (int kt = 0; kt < 512; kt += 64){
    #pragma unroll
    for (int s = 0; s < 4; s++){
      int slot = tid + 256 * s;                // 0..1023
      int r = slot >> 3, cg = slot & 7;
      int sw = (cg ^ (r & 7)) << 3;
      *(uint4*)&As[r * 64 + sw] = *(const uint4*)&Xb[(size_t)(m0 + r) * 512 + kt + cg * 8];
      *(uint4*)&Bs[r * 64 + sw] = *(const uint4*)&Wkv[(size_t)(n0 + r) * 512 + kt + cg * 8];
    }
    __syncthreads();
    #pragma unroll
    for (int ks = 0; ks < 2; ks++){
      bf16x8 af[4], bfr[4];
      int g = ks * 4 + (lane >> 4);
      int ra = wm * 64 + (lane & 15);
      int rb = wn * 64 + (lane & 15);
      #pragma unroll
      for (int i = 0; i < 4; i++){
        int r = ra + i * 16;
        af[i] = *(const bf16x8*)&As[r * 64 + ((g ^ (r & 7)) << 3)];
      }
      #pragma unroll
      for (int j = 0; j < 4; j++){
        int r = rb + j * 16;
        bfr[j] = *(const bf16x8*)&Bs[r * 64 + ((g ^ (r & 7)) << 3)];
      }
      #pragma unroll
      for (int i = 0; i < 4; i++)
        #pragma unroll
        for (int j = 0; j < 4; j++)
          acc[i][j] = __builtin_amdgcn_mfma_f32_16x16x32_bf16(af[i], bfr[j], acc[i][j], 0, 0, 0);
    }
    __syncthreads();
  }

  #pragma unroll
  for (int j = 0; j < 4; j++){
    int n = n0 + wn * 64 + j * 16 + (lane & 15);
    float bias = (n < 512) ? bk[n] : bv[n - 512];
    u16* dst = (n < 512) ? Kb : Vb;
    int nh = (n >> 6) & 7, hd = n & 63;
    #pragma unroll
    for (int i = 0; i < 4; i++){
      #pragma unroll
      for (int r = 0; r < 4; r++){
        int m = m0 + wm * 64 + i * 16 + (lane >> 4) * 4 + r;
        int b = m >> 9, l = m & 511;
        float val = acc[i][j][r] + bias;
        dst[((size_t)((b * 8 + nh) * 512 + l)) * 64 + hd] = f2bf(val);
      }
    }
  }
}

// ---------------- per-step kernels ----------------

// gates GEMM 128 x 2048 x K=1024 over z=[ctx_{t-1}, h_{t-1}] + LSTM + partial q.
__global__ __launch_bounds__(512) void k_gates3(const float* __restrict__ ctxprev, const float* __restrict__ hprev,
                                                float* __restrict__ hnext, float* __restrict__ cbuf,
                                                const float4* __restrict__ Wt4b, const float4* __restrict__ bias4,
                                                const float4* __restrict__ biasx, const float4* __restrict__ xW0,
                                                const float* __restrict__ Wqt, float* __restrict__ qp,
                                                int t0){
  __shared__ __align__(16) float zs[8 * 1024 + 256];   // 32 KB z/psum + 1 KB h-stage
  const int tid = threadIdx.x;
  const int jl = tid & 31, ks = tid >> 5;
  // XCD swizzle: same-jt blocks (sharing the W slice) colocate per XCD.
  const int bid = blockIdx.x;                          // 256 blocks
  const int xcd = bid & 7, idx = bid >> 3;
  const int jt = xcd * 2 + (idx & 1);
  const int bt = idx >> 1;
  const int b0 = bt * 8;
  const int j = jt * 32 + jl;

  // stage z = [ctx(512), h(512)] for 8 b-rows
  for (int i = tid; i < 8 * 256; i += 512){
    int r = i >> 8, c = (i & 255) << 2;
    float4 v;
    if (c < 512){
      if (!t0) v = *(const float4*)&ctxprev[(size_t)(b0 + r) * 512 + c];
      else     v = make_float4(0.f, 0.f, 0.f, 0.f);
    } else {
      v = *(const float4*)&hprev[(size_t)(b0 + r) * 512 + (c - 512)];
    }
    *(float4*)&zs[r * 1024 + c] = v;
  }
  __syncthreads();

  float4 acc[8];
  #pragma unroll
  for (int r = 0; r < 8; r++) acc[r] = make_float4(0.f, 0.f, 0.f, 0.f);

  const int k0 = ks * 64;
  const float4* Wp = Wt4b + (size_t)k0 * 512 + j;
  #pragma unroll 2
  for (int kk = 0; kk < 64; kk += 4){
    float4 w0 = Wp[(size_t)(kk + 0) * 512];
    float4 w1 = Wp[(size_t)(kk + 1) * 512];
    float4 w2 = Wp[(size_t)(kk + 2) * 512];
    float4 w3 = Wp[(size_t)(kk + 3) * 512];
    #pragma unroll
    for (int r = 0; r < 8; r++){
      const float4 xv = *(const float4*)&zs[r * 1024 + k0 + kk];
      acc[r].x += xv.x * w0.x; acc[r].y += xv.x * w0.y; acc[r].z += xv.x * w0.z; acc[r].w += xv.x * w0.w;
      acc[r].x += xv.y * w1.x; acc[r].y += xv.y * w1.y; acc[r].z += xv.y * w1.z; acc[r].w += xv.y * w1.w;
      acc[r].x += xv.z * w2.x; acc[r].y += xv.z * w2.y; acc[r].z += xv.z * w2.z; acc[r].w += xv.z * w2.w;
      acc[r].x += xv.w * w3.x; acc[r].y += xv.w * w3.y; acc[r].z += xv.w * w3.z; acc[r].w += xv.w * w3.w;
    }
  }

  // combine ks pairs within the wave, then 8 wave-partials via LDS
  #pragma unroll
  for (int r = 0; r < 8; r++){
    acc[r].x += __shfl_xor(acc[r].x, 32);
    acc[r].y += __shfl_xor(acc[r].y, 32);
    acc[r].z += __shfl_xor(acc[r].z, 32);
    acc[r].w += __shfl_xor(acc[r].w, 32);
  }
  __syncthreads();                                     // zs reads done; reuse as psum
  float4* ps = (float4*)zs;
  const int lane = tid & 63, wid = tid >> 6;
  if (lane < 32){
    #pragma unroll
    for (int r = 0; r < 8; r++) ps[(wid * 8 + r) * 32 + lane] = acc[r];
  }
  __syncthreads();

  if (tid < 256){
    const int r = tid >> 5, jj = tid & 31;
    const int j2 = jt * 32 + jj;
    float4 a = ps[r * 32 + jj];
    #pragma unroll
    for (int w = 1; w < 8; w++){
      float4 p = ps[(w * 8 + r) * 32 + jj];
      a.x += p.x; a.y += p.y; a.z += p.z; a.w += p.w;
    }
    const int b = b0 + r;
    float4 bb = bias4[j2];
    float4 bx = t0 ? xW0[(size_t)b * 512 + j2] : biasx[j2];
    float ai = a.x + bb.x + bx.x;
    float af = a.y + bb.y + bx.y;
    float ag = a.z + bb.z + bx.z;
    float ao = a.w + bb.w + bx.w;
    float c_old = cbuf[b * 512 + j2];
    float ig = 1.f / (1.f + __expf(-ai));
    float fg = 1.f / (1.f + __expf(-af));
    float e2 = __expf(2.f * ag);
    float gg = 1.f - 2.f / (e2 + 1.f);
    float og = 1.f / (1.f + __expf(-ao));
    float cn = fg * c_old + ig * gg;
    float ec = __expf(2.f * cn);
    float th = 1.f - 2.f / (ec + 1.f);
    cbuf[b * 512 + j2] = cn;
    float hv = og * th;
    hnext[b * 512 + j2] = hv;
    zs[8192 + tid] = hv;                               // h-stage (disjoint from psum)
  }
  __syncthreads();

  // partial q: qp[jt][b0+r][col] = sum_{j<32} h[r][j] * Wqt[jt*32+j][col]
  // threads (rg in 4) x (cgf in 128): each covers rows {rg, rg+4}, one float4
  // of columns -> Wqt read redundancy 4x.
  {
    const int rg = tid >> 7, cgf = tid & 127;
    float4 f0 = make_float4(0.f, 0.f, 0.f, 0.f);
    float4 f1 = make_float4(0.f, 0.f, 0.f, 0.f);
    const float* wq = Wqt + (size_t)(jt * 32) * 512 + cgf * 4;
    const float* hv0 = &zs[8192 + rg * 32];
    const float* hv1 = &zs[8192 + (rg + 4) * 32];
    #pragma unroll 8
    for (int jj = 0; jj < 32; jj++){
      float4 w = *(const float4*)(wq + (size_t)jj * 512);
      float ha = hv0[jj], hb = hv1[jj];
      f0.x += ha * w.x; f0.y += ha * w.y; f0.z += ha * w.z; f0.w += ha * w.w;
      f1.x += hb * w.x; f1.y += hb * w.y; f1.z += hb * w.z; f1.w += hb * w.w;
    }
    float* q0 = qp + ((size_t)jt * 128 + b0 + rg) * 512 + cgf * 4;
    float* q1 = qp + ((size_t)jt * 128 + b0 + rg + 4) * 512 + cgf * 4;
    *(float4*)q0 = f0;
    *(float4*)q1 = f1;
  }
}

// attention v4: coalesced K stream. 512 threads, 8 waves; lane = (rl row,
// ch chunk): each wave K-load covers 8 consecutive rows x 128 B = 1 KB
// contiguous (vs 128B-strided scatter in v3). Chunk dot + shfl_xor(1,2,4)
// builds the row score in-register; softmax reduces over rl via
// shfl_xor(8,16,32); ch-duplicates excluded from the sum by construction.
__global__ __launch_bounds__(512) void k_attn4(const float* __restrict__ qp, const float* __restrict__ bq,
                                               const u16* __restrict__ Kb, const u16* __restrict__ Vb,
                                               float* __restrict__ attn_out, float* __restrict__ ctx_t, int t){
  const int bx = blockIdx.x;
  const int b = bx >> 3, nh = bx & 7;
  const int tid = threadIdx.x;
  const int lane = tid & 63, wid = tid >> 6;     // 8 waves
  const int rl = lane >> 3, ch = lane & 7;
  __shared__ float qs[64];
  __shared__ float sc[512];
  __shared__ float red[20];
  __shared__ __align__(16) float ctxp[8][64];

  // coalesced K prefetch: iter i covers rows wid*64 + i*8 + rl, chunk ch.
  const u16* Kp = Kb + (size_t)bx * (512 * 64);
  uint4 kr[8];
  #pragma unroll
  for (int i = 0; i < 8; i++)
    kr[i] = *(const uint4*)(Kp + (size_t)(wid * 64 + i * 8 + rl) * 64 + ch * 8);

  if (tid < 64){
    float sum = bq[nh * 64 + tid];
    #pragma unroll
    for (int s = 0; s < 16; s++)
      sum += qp[((size_t)s * 128 + b) * 512 + nh * 64 + tid];
    qs[tid] = sum * 0.125f;                      // fold 1/sqrt(HD)
  }
  __syncthreads();

  // chunk dot + cross-chunk reduce -> e[i] = score of row wid*64+i*8+rl
  float e[8];
  float mloc = -3.4e38f;
  {
    const float* q8 = qs + ch * 8;
    #pragma unroll
    for (int i = 0; i < 8; i++){
      uint4 v = kr[i];
      float p = bfbits2f(v.x << 16)          * q8[0];
      p      += bfbits2f(v.x & 0xffff0000u)  * q8[1];
      p      += bfbits2f(v.y << 16)          * q8[2];
      p      += bfbits2f(v.y & 0xffff0000u)  * q8[3];
      p      += bfbits2f(v.z << 16)          * q8[4];
      p      += bfbits2f(v.z & 0xffff0000u)  * q8[5];
      p      += bfbits2f(v.w << 16)          * q8[6];
      p      += bfbits2f(v.w & 0xffff0000u)  * q8[7];
      p += __shfl_xor(p, 1);
      p += __shfl_xor(p, 2);
      p += __shfl_xor(p, 4);
      e[i] = p;
      mloc = fmaxf(mloc, p);
    }
  }

  // V prefetch during softmax (already coalesced: 8 rows x 128 B per inst)
  const int part = wid;
  const u16* vp = Vb + (size_t)bx * (512 * 64) + (size_t)(part * 64 + rl) * 64 + ch * 8;
  uint4 vr[8];
  #pragma unroll
  for (int i = 0; i < 8; i++)
    vr[i] = *(const uint4*)(vp + (size_t)i * 512);   // 8 rows * 64 u16 stride

  // wave max over rl groups (ch duplicates are harmless for max)
  mloc = fmaxf(mloc, __shfl_xor(mloc, 8));
  mloc = fmaxf(mloc, __shfl_xor(mloc, 16));
  mloc = fmaxf(mloc, __shfl_xor(mloc, 32));
  if (lane == 0) red[wid] = mloc;
  __syncthreads();
  if (tid == 0){
    float mm = red[0];
    #pragma unroll
    for (int w = 1; w < 8; w++) mm = fmaxf(mm, red[w]);
    red[16] = mm;
  }
  __syncthreads();
  float mx = red[16];
  float S = 0.f;
  #pragma unroll
  for (int i = 0; i < 8; i++){
    e[i] = __expf(e[i] - mx);
    S += e[i];
  }
  // sum across rl only (each row counted once: this lane's rows are unique per rl)
  S += __shfl_xor(S, 8);
  S += __shfl_xor(S, 16);
  S += __shfl_xor(S, 32);
  if (lane == 0) red[8 + wid] = S;
  __syncthreads();
  if (tid == 0){
    float ss = red[8];
    #pragma unroll
    for (int w = 1; w < 8; w++) ss += red[8 + w];
    red[17] = 1.f / ss;
  }
  __syncthreads();
  float inv = red[17];
  if (ch == 0){
    #pragma unroll
    for (int i = 0; i < 8; i++)
      sc[wid * 64 + i * 8 + rl] = e[i] * inv;
  }
  __syncthreads();
  attn_out[((size_t)bx * HOR_ + t) * 512 + tid] = sc[tid];

  // ctx from prefetched V
  float a[8];
  #pragma unroll
  for (int k = 0; k < 8; k++) a[k] = 0.f;
  #pragma unroll
  for (int i = 0; i < 8; i++){
    int l = part * 64 + i * 8 + rl;
    float w = sc[l];
    uint4 v = vr[i];
    a[0] += w * bfbits2f(v.x << 16);
    a[1] += w * bfbits2f(v.x & 0xffff0000u);
    a[2] += w * bfbits2f(v.y << 16);
    a[3] += w * bfbits2f(v.y & 0xffff0000u);
    a[4] += w * bfbits2f(v.z << 16);
    a[5] += w * bfbits2f(v.z & 0xffff0000u);
    a[6] += w * bfbits2f(v.w << 16);
    a[7] += w * bfbits2f(v.w & 0xffff0000u);
  }
  #pragma unroll
  for (int k = 0; k < 8; k++){
    a[k] += __shfl_xor(a[k], 8);
    a[k] += __shfl_xor(a[k], 16);
    a[k] += __shfl_xor(a[k], 32);
  }
  if (rl == 0){
    float4 c0v = make_float4(a[0], a[1], a[2], a[3]);
    float4 c1v = make_float4(a[4], a[5], a[6], a[7]);
    *(float4*)&ctxp[part][ch * 8] = c0v;
    *(float4*)&ctxp[part][ch * 8 + 4] = c1v;
  }
  __syncthreads();
  if (tid < 64){
    float s = ctxp[0][tid];
    #pragma unroll
    for (int p = 1; p < 8; p++) s += ctxp[p][tid];
    ctx_t[(size_t)b * 512 + nh * 64 + tid] = s;
  }
}

// batched pred (off critical path): pred[b][t] = ctx_all[t][b] @ Mt + bcomb
__global__ __launch_bounds__(256) void k_pred(const float* __restrict__ ctx_all, const float* __restrict__ Mt,
                                              const float* __restrict__ bcomb, float* __restrict__ outp){
  __shared__ float cs[512];
  __shared__ float pr[4][64];
  const int tid = threadIdx.x;
  const int b = blockIdx.x, t = blockIdx.y;
  const float* cx = ctx_all + ((size_t)t * B_ + b) * 512;
  cs[tid] = cx[tid];
  cs[tid + 256] = cx[tid + 256];
  __syncthreads();
  const int p = tid & 63, part = tid >> 6;
  float acc = 0.f;
  const float* mp = Mt + (size_t)(part * 128) * 64 + p;
  const float* cp = &cs[part * 128];
  #pragma unroll 8
  for (int i = 0; i < 128; i++)
    acc += cp[i] * mp[(size_t)i * 64];
  pr[part][p] = acc;
  __syncthreads();
  if (tid < 64){
    float v = pr[0][tid] + pr[1][tid] + pr[2][tid] + pr[3][tid] + bcomb[tid];
    outp[(size_t)b * (HOR_ * OUT_) + t * OUT_ + tid] = v;
  }
}

// ---------------- host launcher ----------------

extern "C" void kernel_launch(void* const* d_in, const int* in_sizes, int n_in,
                              void* d_out, int out_size, void* d_ws, size_t ws_size,
                              hipStream_t stream){
  const float* enc  = (const float*)d_in[0];
  const float* h0   = (const float*)d_in[1];
  const float* c0   = (const float*)d_in[2];
  const float* dec  = (const float*)d_in[3];
  const float* W_ih = (const float*)d_in[4];
  const float* W_hh = (const float*)d_in[5];
  const float* b_ih = (const float*)d_in[6];
  const float* b_hh = (const float*)d_in[7];
  const float* Wq   = (const float*)d_in[8];
  const float* bq   = (const float*)d_in[9];
  const float* Wk   = (const float*)d_in[10];
  const float* bk   = (const float*)d_in[11];
  const float* Wv   = (const float*)d_in[12];
  const float* bv   = (const float*)d_in[13];
  const float* Wo   = (const float*)d_in[14];
  const float* bo   = (const float*)d_in[15];
  const float* Wfc  = (const float*)d_in[16];
  const float* bfc  = (const float*)d_in[17];
  float* out = (float*)d_out;

  char* ws = (char*)d_ws;
  size_t off = 0;
  auto alloc = [&](size_t bytes){ void* p = ws + off; off += (bytes + 255) & ~(size_t)255; return p; };
  u16*   Xb    = (u16*)  alloc((size_t)B_ * L_ * H_ * 2);
  u16*   Kb    = (u16*)  alloc((size_t)B_ * NH_ * L_ * HD_ * 2);
  u16*   Vb    = (u16*)  alloc((size_t)B_ * NH_ * L_ * HD_ * 2);
  u16*   Wkv   = (u16*)  alloc((size_t)1024 * 512 * 2);
  float* Wt4b  = (float*)alloc((size_t)1024 * 512 * 4 * 4);   // [k][j][4 gates]
  float* Wqt   = (float*)alloc((size_t)512 * 512 * 4);
  float* Mt    = (float*)alloc((size_t)512 * 64 * 4);
  float* bcomb = (float*)alloc(64 * 4);
  float* bias4 = (float*)alloc((size_t)2048 * 4);
  float* biasx = (float*)alloc((size_t)2048 * 4);
  float* xW0   = (float*)alloc((size_t)B_ * 2048 * 4);
  float* hb0   = (float*)alloc((size_t)B_ * H_ * 4);
  float* hb1   = (float*)alloc((size_t)B_ * H_ * 4);
  float* cbuf  = (float*)alloc((size_t)B_ * H_ * 4);
  float* qp    = (float*)alloc((size_t)16 * B_ * 512 * 4);    // 16 jt-partials of q
  float* ctx_all = (float*)Xb;                // aliases Xb (dead after k_gemm_kv)
  if (off > ws_size){
    fprintf(stderr, "WORKSPACE TOO SMALL: need %zu, have %zu\n", off, ws_size);
  }

  float* out_pred = out;                                 // (B, HOR, OUT)
  float* out_attn = out + (size_t)B_ * HOR_ * OUT_;      // (B, NH, HOR, L)

  k_convert_x<<<4096, 256, 0, stream>>>((const float4*)enc, (ushort4*)Xb, (B_ * L_ * H_) / 4);
  k_prep<<<7945, 256, 0, stream>>>(Wk, Wv, W_ih, W_hh, b_ih, b_hh, Wq, Wfc, Wo, bo, bfc,
                                   dec, h0, c0, Wkv, Wt4b, Wqt, bias4, Mt, bcomb, xW0, hb0, cbuf);
  k_gemm_kv<<<dim3(8, 512), 256, 0, stream>>>(Xb, Wkv, bk, bv, Kb, Vb);
  k_prep2<<<4097, 256, 0, stream>>>(Mt, W_ih, bcomb, Wt4b, biasx);

  float* hb[2] = {hb0, hb1};
  for (int t = 0; t < HOR_; t++){
    const float* cprev = (t == 0) ? nullptr : (ctx_all + (size_t)(t - 1) * B_ * H_);
    k_gates3<<<256, 512, 0, stream>>>(cprev, hb[t & 1], hb[(t + 1) & 1], cbuf,
                                      (const float4*)Wt4b, (const float4*)bias4,
                                      (const float4*)biasx, (const float4*)xW0,
                                      Wqt, qp, t == 0 ? 1 : 0);
    k_attn4<<<1024, 512, 0, stream>>>(qp, bq, Kb, Vb, out_attn,
                                      ctx_all + (size_t)t * B_ * H_, t);
  }
  k_pred<<<dim3(128, 24), 256, 0, stream>>>(ctx_all, Mt, bcomb, out_pred);
}